// Round 1
// baseline (135.230 us; speedup 1.0000x reference)
//
#include <hip/hip_runtime.h>

typedef unsigned long long u64;
#define EPSF 1e-6f

// ---------------- K1: conv1 1->32ch, 32x32 -> 28x28 ----------------
// grid (4 slabs of 8 oc, 64 img), 256 threads.
// Column-sweep: thread owns (oc, x); slides down rows with a 5-slot acc ring.
__global__ __launch_bounds__(256) void k_conv1(const float* __restrict__ img,
                                               const float* __restrict__ cw1,
                                               const float* __restrict__ cb1,
                                               float* __restrict__ c1) {
  int slab = blockIdx.x, b = blockIdx.y;
  __shared__ float simg[32 * 33];
  for (int k = threadIdx.x; k < 1024; k += 256) {
    int y = k >> 5, x = k & 31;
    simg[y * 33 + x] = img[b * 1024 + k];
  }
  int ocl = threadIdx.x >> 5;
  int x = threadIdx.x & 31;
  int oc = slab * 8 + ocl;
  float w[25];
#pragma unroll
  for (int k = 0; k < 25; ++k) w[k] = cw1[oc * 25 + k];
  float bias = cb1[oc];
  __syncthreads();
  if (x < 28) {
    float acc[5];
#pragma unroll
    for (int k = 0; k < 5; ++k) acc[k] = bias;
    float* outp = c1 + (b * 32 + oc) * 784 + x;
#pragma unroll
    for (int r = 0; r < 32; ++r) {
      float in[5];
#pragma unroll
      for (int c = 0; c < 5; ++c) in[c] = simg[r * 33 + x + c];
#pragma unroll
      for (int ky = 0; ky < 5; ++ky) {
        int y = r - ky;
        if (y < 0 || y > 27) continue;  // compile-time pruned (r,ky unrolled)
#pragma unroll
        for (int kx = 0; kx < 5; ++kx)
          acc[y % 5] = fmaf(w[ky * 5 + kx], in[kx], acc[y % 5]);
      }
      if (r >= 4) {
        int y = r - 4;
        outp[y * 28] = acc[y % 5];
        acc[y % 5] = bias;  // reset slot for row y+5
      }
    }
  }
}

// ---------------- K2: conv2 32->32ch, 28x28 -> 24x24, fused 2x2 maxpool -> 12x12 --------
// grid (4 quarters of 8 oc, 64 img), 192 threads = (icgroup g:4) x (ocg:2 of 4oc) x (row:24).
// Thread computes a full 24-col output row for 4 oc over 8 input channels; 4-way ic reduce in LDS.
__global__ __launch_bounds__(192) void k_conv2(const float* __restrict__ c1,
                                               const float* __restrict__ cw2,
                                               const float* __restrict__ cb2,
                                               float* __restrict__ p1w) {
  int ocq = blockIdx.x, b = blockIdx.y;
  __shared__ float smem[18432];      // 73.7 KB: [w2s 6400 | sl 4*784] then aliased as reduce buf
  float* w2s = smem;                 // layout [(ic*25+kk)*8 + o]
  float* sl = smem + 6400;           // [g][784]
  int t = threadIdx.x;
  int g = t / 48, r48 = t % 48;
  int ocg = r48 / 24, row = r48 % 24;
  {  // stage weights, coalesced reads, transposed LDS writes
    const float4* src = (const float4*)(cw2 + ocq * 8 * 800);
    for (int k4 = t; k4 < 1600; k4 += 192) {
      float4 v = src[k4];
      float vv[4] = {v.x, v.y, v.z, v.w};
      int k = k4 * 4;
#pragma unroll
      for (int r = 0; r < 4; ++r) {
        int kk = k + r;
        int o = kk / 800, rest = kk % 800;
        w2s[rest * 8 + o] = vv[r];
      }
    }
  }
  float acc[4][24];
#pragma unroll
  for (int j = 0; j < 4; ++j)
#pragma unroll
    for (int c = 0; c < 24; ++c) acc[j][c] = 0.f;

  for (int icl = 0; icl < 8; ++icl) {
    int ic = g * 8 + icl;
    __syncthreads();
    {
      const float4* src = (const float4*)(c1 + (b * 32 + ic) * 784);
      float4* dst = (float4*)(sl + g * 784);
      for (int k = r48; k < 196; k += 48) dst[k] = src[k];
    }
    __syncthreads();
#pragma unroll
    for (int ky = 0; ky < 5; ++ky) {
      const float4* rp = (const float4*)(sl + g * 784 + (row + ky) * 28);
      float win[28];
#pragma unroll
      for (int q = 0; q < 7; ++q) {
        float4 v = rp[q];
        win[4 * q] = v.x; win[4 * q + 1] = v.y; win[4 * q + 2] = v.z; win[4 * q + 3] = v.w;
      }
      const float* wb = w2s + (ic * 25 + ky * 5) * 8 + ocg * 4;
#pragma unroll
      for (int kx = 0; kx < 5; ++kx) {
        float wq[4];
        *(float4*)wq = *(const float4*)(wb + kx * 8);
#pragma unroll
        for (int c = 0; c < 24; ++c) {
#pragma unroll
          for (int j = 0; j < 4; ++j) acc[j][c] = fmaf(wq[j], win[c + kx], acc[j][c]);
        }
      }
    }
  }
  __syncthreads();
  float* myred = smem + ((g * 2 + ocg) * 24 + row) * 96;
#pragma unroll
  for (int j = 0; j < 4; ++j)
#pragma unroll
    for (int c = 0; c < 24; ++c) myred[j * 24 + c] = acc[j][c];
  __syncthreads();
  if (g == 0) {
#pragma unroll
    for (int gg = 1; gg < 4; ++gg) {
      const float* rr = smem + ((gg * 2 + ocg) * 24 + row) * 96;
#pragma unroll
      for (int j = 0; j < 4; ++j)
#pragma unroll
        for (int c = 0; c < 24; ++c) acc[j][c] += rr[j * 24 + c];
    }
#pragma unroll
    for (int j = 0; j < 4; ++j) {
      float bias = cb2[ocq * 8 + ocg * 4 + j];
#pragma unroll
      for (int c = 0; c < 24; ++c) myred[j * 24 + c] = acc[j][c] + bias;
    }
  }
  __syncthreads();
  // fused 2x2 maxpool -> p1w[img][32][12][12]
  for (int k = t; k < 1152; k += 192) {
    int o = k / 144, rr2 = k % 144;
    int py = rr2 / 12, px = rr2 % 12;
    int og = o >> 2, j = o & 3;
    const float* b0 = smem + (og * 24 + 2 * py) * 96 + j * 24 + 2 * px;
    float m = fmaxf(fmaxf(b0[0], b0[1]), fmaxf(b0[96], b0[97]));
    p1w[(b * 32 + ocq * 8 + o) * 144 + py * 12 + px] = m;
  }
}

// ---------------- K3: conv3 32->64ch, 12x12 -> 8x8 ----------------
// grid (4 quarters of 16 oc, 64 img), 256 threads = (g:8 icsplit) x (ocg:4) x (row:8).
__global__ __launch_bounds__(256) void k_conv3(const float* __restrict__ p1w,
                                               const float* __restrict__ cw3,
                                               const float* __restrict__ cb3,
                                               float* __restrict__ c3) {
  int ocq = blockIdx.x, b = blockIdx.y;
  __shared__ float smem[17408];    // w3s 12800 | ins 4608 ; reduce aliases [0,8192)
  float* w3s = smem;
  float* ins = smem + 12800;
  int t = threadIdx.x;
  {
    const float4* src = (const float4*)(p1w + b * 32 * 144);
    float4* dst = (float4*)ins;
    for (int k = t; k < 1152; k += 256) dst[k] = src[k];
  }
  {
    const float4* src = (const float4*)(cw3 + ocq * 16 * 800);
    for (int k4 = t; k4 < 3200; k4 += 256) {
      float4 v = src[k4];
      float vv[4] = {v.x, v.y, v.z, v.w};
      int k = k4 * 4;
#pragma unroll
      for (int r = 0; r < 4; ++r) {
        int kk = k + r;
        int o = kk / 800, rest = kk % 800;
        w3s[rest * 16 + o] = vv[r];
      }
    }
  }
  int g = t >> 5, r32 = t & 31;
  int ocg = r32 >> 3, row = r32 & 7;
  float acc[4][8];
#pragma unroll
  for (int j = 0; j < 4; ++j)
#pragma unroll
    for (int c = 0; c < 8; ++c) acc[j][c] = 0.f;
  __syncthreads();
#pragma unroll
  for (int icl = 0; icl < 4; ++icl) {
    int ic = g * 4 + icl;
#pragma unroll
    for (int ky = 0; ky < 5; ++ky) {
      const float4* rp = (const float4*)(ins + ic * 144 + (row + ky) * 12);
      float win[12];
#pragma unroll
      for (int q = 0; q < 3; ++q) {
        float4 v = rp[q];
        win[4 * q] = v.x; win[4 * q + 1] = v.y; win[4 * q + 2] = v.z; win[4 * q + 3] = v.w;
      }
      const float* wb = w3s + (ic * 25 + ky * 5) * 16 + ocg * 4;
#pragma unroll
      for (int kx = 0; kx < 5; ++kx) {
        float wq[4];
        *(float4*)wq = *(const float4*)(wb + kx * 16);
#pragma unroll
        for (int c = 0; c < 8; ++c) {
#pragma unroll
          for (int j = 0; j < 4; ++j) acc[j][c] = fmaf(wq[j], win[c + kx], acc[j][c]);
        }
      }
    }
  }
  __syncthreads();
  float* myred = smem + t * 32;
#pragma unroll
  for (int j = 0; j < 4; ++j)
#pragma unroll
    for (int c = 0; c < 8; ++c) myred[j * 8 + c] = acc[j][c];
  __syncthreads();
  if (g == 0) {
#pragma unroll
    for (int gg = 1; gg < 8; ++gg) {
      const float* rr = smem + (gg * 32 + r32) * 32;
#pragma unroll
      for (int j = 0; j < 4; ++j)
#pragma unroll
        for (int c = 0; c < 8; ++c) acc[j][c] += rr[j * 8 + c];
    }
#pragma unroll
    for (int j = 0; j < 4; ++j) {
      float bias = cb3[ocq * 16 + ocg * 4 + j];
#pragma unroll
      for (int c = 0; c < 8; ++c)
        c3[(b * 64 + ocq * 16 + ocg * 4 + j) * 64 + row * 8 + c] = acc[j][c] + bias;
    }
  }
}

// ---------------- K4: conv4 64->64ch, 8x8 -> 4x4, fused pool -> emb[256] ----------------
// grid (4 quarters of 16 oc, 64 img), 256 threads = (g:16 icsplit) x (ocg:4) x (row:4).
__global__ __launch_bounds__(256) void k_conv4(const float* __restrict__ c3,
                                               const float* __restrict__ cw4,
                                               const float* __restrict__ cb4,
                                               float* __restrict__ emb) {
  int ocq = blockIdx.x, b = blockIdx.y;
  __shared__ float smem[29696];   // w4s 25600 | ins 4096 ; reduce aliases [0,4096)
  float* w4s = smem;
  float* ins = smem + 25600;
  int t = threadIdx.x;
  {
    const float4* src = (const float4*)(c3 + b * 4096);
    float4* dst = (float4*)ins;
    for (int k = t; k < 1024; k += 256) dst[k] = src[k];
  }
  {
    const float4* src = (const float4*)(cw4 + ocq * 16 * 1600);
    for (int k4 = t; k4 < 6400; k4 += 256) {
      float4 v = src[k4];
      float vv[4] = {v.x, v.y, v.z, v.w};
      int k = k4 * 4;
#pragma unroll
      for (int r = 0; r < 4; ++r) {
        int kk = k + r;
        int o = kk / 1600, rest = kk % 1600;
        w4s[rest * 16 + o] = vv[r];
      }
    }
  }
  int g = t >> 4, r16 = t & 15;
  int ocg = r16 >> 2, row = r16 & 3;
  float acc[4][4];
#pragma unroll
  for (int j = 0; j < 4; ++j)
#pragma unroll
    for (int c = 0; c < 4; ++c) acc[j][c] = 0.f;
  __syncthreads();
#pragma unroll
  for (int icl = 0; icl < 4; ++icl) {
    int ic = g * 4 + icl;
#pragma unroll
    for (int ky = 0; ky < 5; ++ky) {
      const float4* rp = (const float4*)(ins + ic * 64 + (row + ky) * 8);
      float win[8];
#pragma unroll
      for (int q = 0; q < 2; ++q) {
        float4 v = rp[q];
        win[4 * q] = v.x; win[4 * q + 1] = v.y; win[4 * q + 2] = v.z; win[4 * q + 3] = v.w;
      }
      const float* wb = w4s + (ic * 25 + ky * 5) * 16 + ocg * 4;
#pragma unroll
      for (int kx = 0; kx < 5; ++kx) {
        float wq[4];
        *(float4*)wq = *(const float4*)(wb + kx * 16);
#pragma unroll
        for (int c = 0; c < 4; ++c) {
#pragma unroll
          for (int j = 0; j < 4; ++j) acc[j][c] = fmaf(wq[j], win[c + kx], acc[j][c]);
        }
      }
    }
  }
  __syncthreads();
  float* myred = smem + t * 16;
#pragma unroll
  for (int j = 0; j < 4; ++j)
#pragma unroll
    for (int c = 0; c < 4; ++c) myred[j * 4 + c] = acc[j][c];
  __syncthreads();
  if (g == 0) {
#pragma unroll
    for (int gg = 1; gg < 16; ++gg) {
      const float* rr = smem + (gg * 16 + r16) * 16;
#pragma unroll
      for (int j = 0; j < 4; ++j)
#pragma unroll
        for (int c = 0; c < 4; ++c) acc[j][c] += rr[j * 4 + c];
    }
#pragma unroll
    for (int j = 0; j < 4; ++j) {
      float bias = cb4[ocq * 16 + ocg * 4 + j];
#pragma unroll
      for (int c = 0; c < 4; ++c) myred[j * 4 + c] = acc[j][c] + bias;
    }
  }
  __syncthreads();
  if (t < 64) {  // 2x2 pool -> emb
    int o = t >> 2, q = t & 3, py = q >> 1, px = q & 1;
    int og = o >> 2, j = o & 3;
    const float* b0 = smem + (og * 4 + 2 * py) * 16 + j * 4 + 2 * px;
    float m = fmaxf(fmaxf(b0[0], b0[1]), fmaxf(b0[16], b0[17]));
    emb[b * 256 + (ocq * 16 + o) * 4 + py * 2 + px] = m;
  }
}

// ---------------- K5a: MLP heads -> pc, log(pc), log1p(-pc), logcat ----------------
// grid (2 heads, 64 img), 256 threads
__global__ __launch_bounds__(256) void k_heads(const float* __restrict__ emb,
    const float* __restrict__ wc1, const float* __restrict__ bc1,
    const float* __restrict__ wc2, const float* __restrict__ bc2,
    const float* __restrict__ we1, const float* __restrict__ be1,
    const float* __restrict__ we2, const float* __restrict__ be2,
    float* __restrict__ pcw, float* __restrict__ lpcw,
    float* __restrict__ l1mw, float* __restrict__ lcatw) {
  int head = blockIdx.x, b = blockIdx.y;
  int t = threadIdx.x;
  __shared__ float e_s[256], h_s[256];
  __shared__ float aux;
  e_s[t] = emb[b * 256 + t];
  __syncthreads();
  const float* W1 = head ? we1 : wc1;
  const float* B1 = head ? be1 : bc1;
  float s = B1[t];
  for (int i = 0; i < 256; i += 4) {
    s = fmaf(e_s[i], W1[i * 256 + t], s);
    s = fmaf(e_s[i + 1], W1[(i + 1) * 256 + t], s);
    s = fmaf(e_s[i + 2], W1[(i + 2) * 256 + t], s);
    s = fmaf(e_s[i + 3], W1[(i + 3) * 256 + t], s);
  }
  h_s[t] = fmaxf(s, 0.f);
  __syncthreads();
  int NO = head ? 36 : 120;
  const float* W2 = head ? we2 : wc2;
  const float* B2 = head ? be2 : bc2;
  if (t < NO) {
    float s2 = B2[t];
    for (int i = 0; i < 256; ++i) s2 = fmaf(h_s[i], W2[i * NO + t], s2);
    float p = 1.f / (1.f + expf(-s2));
    p = fminf(fmaxf(p, EPSF), 1.f - EPSF);
    if (head == 0) {
      pcw[b * 120 + t] = p;
      lpcw[b * 120 + t] = logf(p);
      l1mw[b * 120 + t] = log1pf(-p);
    } else {
      e_s[t] = p;  // reuse as pe storage
    }
  }
  if (head == 1) {
    __syncthreads();
    if (t == 0) {
      float sm = 0.f;
      for (int j2 = 0; j2 < 36; ++j2) sm += e_s[j2];
      aux = sm;
    }
    __syncthreads();
    if (t < 36) lcatw[b * 36 + t] = logf(e_s[t] / aux);
  }
}

// ---------------- K5b: Monte-Carlo sampling + bitmask reachability + softmax ----------------
// grid 64 (img), 256 threads (1 thread = 1 sample)
__global__ __launch_bounds__(256) void k_mc(const float* __restrict__ enoise,
    const float* __restrict__ us, const float* __restrict__ ud,
    const int* __restrict__ edges,
    const float* __restrict__ pcw, const float* __restrict__ lpcw,
    const float* __restrict__ l1mw, const float* __restrict__ lcatw,
    float* __restrict__ out) {
  int b = blockIdx.x, t = threadIdx.x;
  __shared__ __align__(16) float pc_s[120];
  __shared__ __align__(16) float lpc_s[120];
  __shared__ __align__(16) float l1m_s[120];
  __shared__ __align__(16) float lcat_s[36];
  __shared__ __align__(16) int einfo[120];
  __shared__ float red_s[256];
  if (t < 120) {
    pc_s[t] = pcw[b * 120 + t];
    lpc_s[t] = lpcw[b * 120 + t];
    l1m_s[t] = l1mw[b * 120 + t];
    int u = edges[2 * t], v = edges[2 * t + 1];
    int d = v - u;
    int isV = (d == 6 || d == -6) ? 1 : 0;
    int pos = d > 0 ? u : v;
    einfo[t] = pos | (isV << 6);
  }
  if (t < 36) lcat_s[t] = lcatw[b * 36 + t];
  __syncthreads();

  // Bernoulli edges -> logw + H/V bitmasks
  float logw = 0.f;
  u64 H = 0, V = 0;
  {
    const float4* np = (const float4*)(enoise + ((size_t)(b * 256 + t)) * 120);
#pragma unroll
    for (int q = 0; q < 30; ++q) {
      float4 nz = np[q];
      float4 p4 = ((const float4*)pc_s)[q];
      float4 lp4 = ((const float4*)lpc_s)[q];
      float4 lm4 = ((const float4*)l1m_s)[q];
      int4 e4 = ((const int4*)einfo)[q];
      float nv[4] = {nz.x, nz.y, nz.z, nz.w};
      float pv[4] = {p4.x, p4.y, p4.z, p4.w};
      float lv[4] = {lp4.x, lp4.y, lp4.z, lp4.w};
      float mv[4] = {lm4.x, lm4.y, lm4.z, lm4.w};
      int ev[4] = {e4.x, e4.y, e4.z, e4.w};
#pragma unroll
      for (int r = 0; r < 4; ++r) {
        bool conn = nv[r] < pv[r];
        logw += conn ? lv[r] : mv[r];
        if (conn) {
          u64 bit = 1ull << (ev[r] & 63);
          if (ev[r] & 64) V |= bit; else H |= bit;
        }
      }
    }
  }
  // Gumbel argmax for source and destination
  int si = 0, di = 0;
  {
    const float4* up = (const float4*)(us + ((size_t)(b * 256 + t)) * 36);
    float best = -1e30f;
#pragma unroll
    for (int q = 0; q < 9; ++q) {
      float4 uv = up[q];
      float4 lc4 = ((const float4*)lcat_s)[q];
      float vv[4] = {uv.x, uv.y, uv.z, uv.w};
      float lc[4] = {lc4.x, lc4.y, lc4.z, lc4.w};
#pragma unroll
      for (int r = 0; r < 4; ++r) {
        float u = fminf(fmaxf(vv[r], EPSF), 1.f - EPSF);
        float gq = -logf(-logf(u));
        float val = lc[r] + gq;
        if (val > best) { best = val; si = q * 4 + r; }
      }
    }
  }
  {
    const float4* up = (const float4*)(ud + ((size_t)(b * 256 + t)) * 36);
    float best = -1e30f;
#pragma unroll
    for (int q = 0; q < 9; ++q) {
      float4 uv = up[q];
      float4 lc4 = ((const float4*)lcat_s)[q];
      float vv[4] = {uv.x, uv.y, uv.z, uv.w};
      float lc[4] = {lc4.x, lc4.y, lc4.z, lc4.w};
#pragma unroll
      for (int r = 0; r < 4; ++r) {
        float u = fminf(fmaxf(vv[r], EPSF), 1.f - EPSF);
        float gq = -logf(-logf(u));
        float val = lc[r] + gq;
        if (val > best) { best = val; di = q * 4 + r; }
      }
    }
  }
  logw += lcat_s[si] + lcat_s[di];

  // bit-parallel connectivity closure on the 6x6 grid (36 bits in a u64)
  u64 comp = 1ull << si;
  while (true) {
    u64 prev = comp;
    comp |= ((comp & H) << 1) | ((comp >> 1) & H);
    comp |= ((comp & V) << 6) | ((comp >> 6) & V);
    if (comp == prev) break;
  }
  float ex;
  if (si == di) ex = (comp != (1ull << si)) ? 1.f : 0.f;   // needs >=1 incident active edge
  else ex = ((comp >> di) & 1ull) ? 1.f : 0.f;

  // block softmax over 256 samples
  red_s[t] = logw; __syncthreads();
  for (int off = 128; off > 0; off >>= 1) {
    if (t < off) red_s[t] = fmaxf(red_s[t], red_s[t + off]);
    __syncthreads();
  }
  float m = red_s[0]; __syncthreads();
  float evx = expf(logw - m);
  red_s[t] = evx; __syncthreads();
  for (int off = 128; off > 0; off >>= 1) {
    if (t < off) red_s[t] += red_s[t + off];
    __syncthreads();
  }
  float den = red_s[0]; __syncthreads();
  red_s[t] = evx * ex; __syncthreads();
  for (int off = 128; off > 0; off >>= 1) {
    if (t < off) red_s[t] += red_s[t + off];
    __syncthreads();
  }
  if (t == 0) {
    float p1v = red_s[0] / den;
    out[b * 2] = 1.f - p1v;
    out[b * 2 + 1] = p1v;
  }
}

extern "C" void kernel_launch(void* const* d_in, const int* in_sizes, int n_in,
                              void* d_out, int out_size, void* d_ws, size_t ws_size,
                              hipStream_t stream) {
  const float* image = (const float*)d_in[0];
  const float* enoise = (const float*)d_in[1];
  const float* us = (const float*)d_in[2];
  const float* udn = (const float*)d_in[3];
  const float* cw1 = (const float*)d_in[4];
  const float* cb1 = (const float*)d_in[5];
  const float* cw2 = (const float*)d_in[6];
  const float* cb2 = (const float*)d_in[7];
  const float* cw3 = (const float*)d_in[8];
  const float* cb3 = (const float*)d_in[9];
  const float* cw4 = (const float*)d_in[10];
  const float* cb4 = (const float*)d_in[11];
  const float* wc1 = (const float*)d_in[12];
  const float* bc1 = (const float*)d_in[13];
  const float* wc2 = (const float*)d_in[14];
  const float* bc2 = (const float*)d_in[15];
  const float* we1 = (const float*)d_in[16];
  const float* be1 = (const float*)d_in[17];
  const float* we2 = (const float*)d_in[18];
  const float* be2 = (const float*)d_in[19];
  const int* edges = (const int*)d_in[20];

  // workspace layout (floats): needs ~8.82 MB
  float* ws = (float*)d_ws;
  float* c1 = ws;                  // 64*32*784   = 1,605,632
  float* p1w = ws + 1605632;       // 64*32*144   =   294,912
  float* c3 = ws + 1900544;        // 64*64*64    =   262,144
  float* emb = ws + 2162688;       // 64*256      =    16,384
  float* pcw = ws + 2179072;       // 64*120
  float* lpcw = ws + 2186752;      // 64*120
  float* l1mw = ws + 2194432;      // 64*120
  float* lcatw = ws + 2202112;     // 64*36
  float* outp = (float*)d_out;

  k_conv1<<<dim3(4, 64), dim3(256), 0, stream>>>(image, cw1, cb1, c1);
  k_conv2<<<dim3(4, 64), dim3(192), 0, stream>>>(c1, cw2, cb2, p1w);
  k_conv3<<<dim3(4, 64), dim3(256), 0, stream>>>(p1w, cw3, cb3, c3);
  k_conv4<<<dim3(4, 64), dim3(256), 0, stream>>>(c3, cw4, cb4, emb);
  k_heads<<<dim3(2, 64), dim3(256), 0, stream>>>(emb, wc1, bc1, wc2, bc2,
                                                 we1, be1, we2, be2,
                                                 pcw, lpcw, l1mw, lcatw);
  k_mc<<<dim3(64), dim3(256), 0, stream>>>(enoise, us, udn, edges,
                                           pcw, lpcw, l1mw, lcatw, outp);
}

// Round 2
// 134.470 us; speedup vs baseline: 1.0056x; 1.0056x over previous
//
#include <hip/hip_runtime.h>

typedef unsigned long long u64;
#define EPSF 1e-6f

// ---------------- K1: conv1 1->32ch, 32x32 -> 28x28 ----------------
// grid (4 slabs of 8 oc, 64 img), 512 threads = (rowhalf:2) x (oc:8) x (x:32).
__global__ __launch_bounds__(512) void k_conv1(const float* __restrict__ img,
                                               const float* __restrict__ cw1,
                                               const float* __restrict__ cb1,
                                               float* __restrict__ c1) {
  int slab = blockIdx.x, b = blockIdx.y;
  __shared__ float simg[32 * 33];
  for (int k = threadIdx.x; k < 1024; k += 512) {
    int y = k >> 5, x = k & 31;
    simg[y * 33 + x] = img[b * 1024 + k];
  }
  int half = threadIdx.x >> 8;      // 0: out rows 0..13, 1: rows 14..27
  int u = threadIdx.x & 255;
  int ocl = u >> 5;
  int x = u & 31;
  int oc = slab * 8 + ocl;
  int y0 = half * 14;
  float w[25];
#pragma unroll
  for (int k = 0; k < 25; ++k) w[k] = cw1[oc * 25 + k];
  float bias = cb1[oc];
  __syncthreads();
  if (x < 28) {
    float acc[5];
#pragma unroll
    for (int k = 0; k < 5; ++k) acc[k] = bias;
    float* outp = c1 + (b * 32 + oc) * 784 + x;
#pragma unroll
    for (int rr = 0; rr < 18; ++rr) {
      int r = y0 + rr;
      float in[5];
#pragma unroll
      for (int c = 0; c < 5; ++c) in[c] = simg[r * 33 + x + c];
#pragma unroll
      for (int ky = 0; ky < 5; ++ky) {
        if (rr < ky || rr - ky > 13) continue;  // compile-time pruned
        int slot = (rr - ky) % 5;
#pragma unroll
        for (int kx = 0; kx < 5; ++kx)
          acc[slot] = fmaf(w[ky * 5 + kx], in[kx], acc[slot]);
      }
      if (rr >= 4) {
        int slot = (rr - 4) % 5;
        outp[(y0 + rr - 4) * 28] = acc[slot];
        acc[slot] = bias;
      }
    }
  }
}

// ---------------- K2: conv2 32->32ch, 28x28 -> 24x24, fused 2x2 maxpool -> 12x12 --------
// grid (4 ocq of 8oc, 2 rowhalf, 64 img) = 512 blocks, 384 threads.
// t = g(8, ic-split) x 48 = (ocg:4 of 2oc) x (row:12). acc[2][24] per thread.
__global__ __launch_bounds__(384) void k_conv2(const float* __restrict__ c1,
                                               const float* __restrict__ cw2,
                                               const float* __restrict__ cb2,
                                               float* __restrict__ p1w) {
  int ocq = blockIdx.x, rh = blockIdx.y, b = blockIdx.z;
  __shared__ float smem[9984];   // 39.9 KB: [w2s 6400 | sl 8*448] ; reduce/pool alias [0..)
  float* w2s = smem;             // [(ic*25+kk)*8 + o]
  float* sl = smem + 6400;       // [g][448] = 16 rows x 28
  int t = threadIdx.x;
  int g = t / 48, p = t % 48;
  int ocg = p / 12, row = p % 12;
  {  // stage weights: 8 oc x 800, transposed
    const float4* src = (const float4*)(cw2 + ocq * 8 * 800);
    for (int k4 = t; k4 < 1600; k4 += 384) {
      float4 v = src[k4];
      float vv[4] = {v.x, v.y, v.z, v.w};
      int k = k4 * 4;
#pragma unroll
      for (int r = 0; r < 4; ++r) {
        int kk = k + r;
        int o = kk / 800, rest = kk % 800;
        w2s[rest * 8 + o] = vv[r];
      }
    }
  }
  float acc[2][24];
#pragma unroll
  for (int j = 0; j < 2; ++j)
#pragma unroll
    for (int c = 0; c < 24; ++c) acc[j][c] = 0.f;

  int r0 = rh * 12;  // first output row of this block
#pragma unroll
  for (int icl = 0; icl < 4; ++icl) {
    int ic = g + icl * 8;
    __syncthreads();
    {  // stage 16 input rows of this g's ic
      const float4* src = (const float4*)(c1 + (b * 32 + ic) * 784 + r0 * 28);
      float4* dst = (float4*)(sl + g * 448);
      for (int k = p; k < 112; k += 48) dst[k] = src[k];
    }
    __syncthreads();
#pragma unroll
    for (int ky = 0; ky < 5; ++ky) {
      const float4* rp = (const float4*)(sl + g * 448 + (row + ky) * 28);
      float win[28];
#pragma unroll
      for (int q = 0; q < 7; ++q) {
        float4 v = rp[q];
        win[4 * q] = v.x; win[4 * q + 1] = v.y; win[4 * q + 2] = v.z; win[4 * q + 3] = v.w;
      }
      const float* wb = w2s + (ic * 25 + ky * 5) * 8 + ocg * 2;
#pragma unroll
      for (int kx = 0; kx < 5; ++kx) {
        float2 wv = *(const float2*)(wb + kx * 8);
#pragma unroll
        for (int c = 0; c < 24; ++c) {
          acc[0][c] = fmaf(wv.x, win[c + kx], acc[0][c]);
          acc[1][c] = fmaf(wv.y, win[c + kx], acc[1][c]);
        }
      }
    }
  }
  // 8-way ic reduce tree, chunk = 48 pos x 48 floats = 2304
  float* buf = smem;
  __syncthreads();
  if (g >= 4) {
    float* d = buf + (g - 4) * 2304 + p * 48;
#pragma unroll
    for (int j = 0; j < 2; ++j)
#pragma unroll
      for (int c = 0; c < 24; ++c) d[j * 24 + c] = acc[j][c];
  }
  __syncthreads();
  if (g < 4) {
    const float* s = buf + g * 2304 + p * 48;
#pragma unroll
    for (int j = 0; j < 2; ++j)
#pragma unroll
      for (int c = 0; c < 24; ++c) acc[j][c] += s[j * 24 + c];
  }
  __syncthreads();
  if (g == 2 || g == 3) {
    float* d = buf + (g - 2) * 2304 + p * 48;
#pragma unroll
    for (int j = 0; j < 2; ++j)
#pragma unroll
      for (int c = 0; c < 24; ++c) d[j * 24 + c] = acc[j][c];
  }
  __syncthreads();
  if (g < 2) {
    const float* s = buf + g * 2304 + p * 48;
#pragma unroll
    for (int j = 0; j < 2; ++j)
#pragma unroll
      for (int c = 0; c < 24; ++c) acc[j][c] += s[j * 24 + c];
  }
  __syncthreads();
  if (g == 1) {
    float* d = buf + p * 48;
#pragma unroll
    for (int j = 0; j < 2; ++j)
#pragma unroll
      for (int c = 0; c < 24; ++c) d[j * 24 + c] = acc[j][c];
  }
  __syncthreads();
  float* pb = buf + 2304;  // pool buffer: [8 oc][12 rows][24 cols]
  if (g == 0) {
    const float* s = buf + p * 48;
#pragma unroll
    for (int j = 0; j < 2; ++j) {
      float bias = cb2[ocq * 8 + ocg * 2 + j];
#pragma unroll
      for (int c = 0; c < 24; ++c)
        pb[(ocg * 2 + j) * 288 + row * 24 + c] = acc[j][c] + s[j * 24 + c] + bias;
    }
  }
  __syncthreads();
  // 2x2 maxpool -> p1w[img][32][12][12]
  for (int k = t; k < 576; k += 384) {
    int o = k / 72, rem = k % 72;
    int py = rem / 12, px = rem % 12;
    const float* b0 = pb + o * 288 + (2 * py) * 24 + 2 * px;
    float m = fmaxf(fmaxf(b0[0], b0[1]), fmaxf(b0[24], b0[25]));
    p1w[(b * 32 + ocq * 8 + o) * 144 + (rh * 6 + py) * 12 + px] = m;
  }
}

// ---------------- K3: conv3 32->64ch, 12x12 -> 8x8 ----------------
// grid (8 groups of 8 oc, 64 img) = 512 blocks, 256 threads = g:16(2ic) x (ocg:2 x row:8).
__global__ __launch_bounds__(256) void k_conv3(const float* __restrict__ p1w,
                                               const float* __restrict__ cw3,
                                               const float* __restrict__ cb3,
                                               float* __restrict__ c3) {
  int oc8 = blockIdx.x, b = blockIdx.y;
  __shared__ float smem[11008];  // w3s 6400 | ins 4608 ; reduce aliases [0..4096)
  float* w3s = smem;
  float* ins = smem + 6400;
  int t = threadIdx.x;
  {
    const float4* src = (const float4*)(p1w + b * 32 * 144);
    float4* dst = (float4*)ins;
    for (int k = t; k < 1152; k += 256) dst[k] = src[k];
  }
  {
    const float4* src = (const float4*)(cw3 + oc8 * 8 * 800);
    for (int k4 = t; k4 < 1600; k4 += 256) {
      float4 v = src[k4];
      float vv[4] = {v.x, v.y, v.z, v.w};
      int k = k4 * 4;
#pragma unroll
      for (int r = 0; r < 4; ++r) {
        int kk = k + r;
        int o = kk / 800, rest = kk % 800;
        w3s[rest * 8 + o] = vv[r];
      }
    }
  }
  int g = t >> 4, p = t & 15;
  int ocg = p >> 3, row = p & 7;
  float acc[4][8];
#pragma unroll
  for (int j = 0; j < 4; ++j)
#pragma unroll
    for (int c = 0; c < 8; ++c) acc[j][c] = 0.f;
  __syncthreads();
#pragma unroll
  for (int icl = 0; icl < 2; ++icl) {
    int ic = g + icl * 16;
#pragma unroll
    for (int ky = 0; ky < 5; ++ky) {
      const float4* rp = (const float4*)(ins + ic * 144 + (row + ky) * 12);
      float win[12];
#pragma unroll
      for (int q = 0; q < 3; ++q) {
        float4 v = rp[q];
        win[4 * q] = v.x; win[4 * q + 1] = v.y; win[4 * q + 2] = v.z; win[4 * q + 3] = v.w;
      }
      const float* wb = w3s + (ic * 25 + ky * 5) * 8 + ocg * 4;
#pragma unroll
      for (int kx = 0; kx < 5; ++kx) {
        float wq[4];
        *(float4*)wq = *(const float4*)(wb + kx * 8);
#pragma unroll
        for (int c = 0; c < 8; ++c) {
#pragma unroll
          for (int j = 0; j < 4; ++j) acc[j][c] = fmaf(wq[j], win[c + kx], acc[j][c]);
        }
      }
    }
  }
  // 16-way reduce tree, chunk = 16 pos x 32 = 512 floats
  float* buf = smem;
  __syncthreads();
  if (g >= 8) {
    float* d = buf + (g - 8) * 512 + p * 32;
#pragma unroll
    for (int j = 0; j < 4; ++j)
#pragma unroll
      for (int c = 0; c < 8; ++c) d[j * 8 + c] = acc[j][c];
  }
  __syncthreads();
  if (g < 8) {
    const float* s = buf + g * 512 + p * 32;
#pragma unroll
    for (int j = 0; j < 4; ++j)
#pragma unroll
      for (int c = 0; c < 8; ++c) acc[j][c] += s[j * 8 + c];
  }
  __syncthreads();
  if (g >= 4 && g < 8) {
    float* d = buf + (g - 4) * 512 + p * 32;
#pragma unroll
    for (int j = 0; j < 4; ++j)
#pragma unroll
      for (int c = 0; c < 8; ++c) d[j * 8 + c] = acc[j][c];
  }
  __syncthreads();
  if (g < 4) {
    const float* s = buf + g * 512 + p * 32;
#pragma unroll
    for (int j = 0; j < 4; ++j)
#pragma unroll
      for (int c = 0; c < 8; ++c) acc[j][c] += s[j * 8 + c];
  }
  __syncthreads();
  if (g == 2 || g == 3) {
    float* d = buf + (g - 2) * 512 + p * 32;
#pragma unroll
    for (int j = 0; j < 4; ++j)
#pragma unroll
      for (int c = 0; c < 8; ++c) d[j * 8 + c] = acc[j][c];
  }
  __syncthreads();
  if (g < 2) {
    const float* s = buf + g * 512 + p * 32;
#pragma unroll
    for (int j = 0; j < 4; ++j)
#pragma unroll
      for (int c = 0; c < 8; ++c) acc[j][c] += s[j * 8 + c];
  }
  __syncthreads();
  if (g == 1) {
    float* d = buf + p * 32;
#pragma unroll
    for (int j = 0; j < 4; ++j)
#pragma unroll
      for (int c = 0; c < 8; ++c) d[j * 8 + c] = acc[j][c];
  }
  __syncthreads();
  if (g == 0) {
    const float* s = buf + p * 32;
#pragma unroll
    for (int j = 0; j < 4; ++j) {
      float bias = cb3[oc8 * 8 + ocg * 4 + j];
      float4 v0, v1;
      v0.x = acc[j][0] + s[j * 8 + 0] + bias; v0.y = acc[j][1] + s[j * 8 + 1] + bias;
      v0.z = acc[j][2] + s[j * 8 + 2] + bias; v0.w = acc[j][3] + s[j * 8 + 3] + bias;
      v1.x = acc[j][4] + s[j * 8 + 4] + bias; v1.y = acc[j][5] + s[j * 8 + 5] + bias;
      v1.z = acc[j][6] + s[j * 8 + 6] + bias; v1.w = acc[j][7] + s[j * 8 + 7] + bias;
      float* op = c3 + (b * 64 + oc8 * 8 + ocg * 4 + j) * 64 + row * 8;
      *(float4*)op = v0; *(float4*)(op + 4) = v1;
    }
  }
}

// ---------------- K4: conv4 64->64ch, 8x8 -> 4x4, fused pool -> emb[256] ----------------
// grid (8 groups of 8 oc, 64 img) = 512 blocks, 256 threads = g:32(2ic) x (ocg:2 x row:4).
__global__ __launch_bounds__(256) void k_conv4(const float* __restrict__ c3,
                                               const float* __restrict__ cw4,
                                               const float* __restrict__ cb4,
                                               float* __restrict__ emb) {
  int oc8 = blockIdx.x, b = blockIdx.y;
  __shared__ float smem[17152];  // w4s 12800 | ins 64*68 ; reduce aliases [0..2048), pb @2048
  float* w4s = smem;
  float* ins = smem + 12800;     // padded stride 68 per ic
  int t = threadIdx.x;
  {
    const float4* src = (const float4*)(c3 + b * 4096);
    for (int k = t; k < 1024; k += 256) {
      int ic = k >> 4, q = k & 15;
      *(float4*)(ins + ic * 68 + q * 4) = src[k];
    }
  }
  {
    const float4* src = (const float4*)(cw4 + oc8 * 8 * 1600);
    for (int k4 = t; k4 < 3200; k4 += 256) {
      float4 v = src[k4];
      float vv[4] = {v.x, v.y, v.z, v.w};
      int k = k4 * 4;
#pragma unroll
      for (int r = 0; r < 4; ++r) {
        int kk = k + r;
        int o = kk / 1600, rest = kk % 1600;
        w4s[rest * 8 + o] = vv[r];
      }
    }
  }
  int g = t >> 3, p = t & 7;
  int ocg = p >> 2, row = p & 3;
  float acc[4][4];
#pragma unroll
  for (int j = 0; j < 4; ++j)
#pragma unroll
    for (int c = 0; c < 4; ++c) acc[j][c] = 0.f;
  __syncthreads();
#pragma unroll
  for (int icl = 0; icl < 2; ++icl) {
    int ic = g + icl * 32;
#pragma unroll
    for (int ky = 0; ky < 5; ++ky) {
      const float4* rp = (const float4*)(ins + ic * 68 + (row + ky) * 8);
      float win[8];
#pragma unroll
      for (int q = 0; q < 2; ++q) {
        float4 v = rp[q];
        win[4 * q] = v.x; win[4 * q + 1] = v.y; win[4 * q + 2] = v.z; win[4 * q + 3] = v.w;
      }
      const float* wb = w4s + (ic * 25 + ky * 5) * 8 + ocg * 4;
#pragma unroll
      for (int kx = 0; kx < 5; ++kx) {
        float wq[4];
        *(float4*)wq = *(const float4*)(wb + kx * 8);
#pragma unroll
        for (int c = 0; c < 4; ++c) {
#pragma unroll
          for (int j = 0; j < 4; ++j) acc[j][c] = fmaf(wq[j], win[c + kx], acc[j][c]);
        }
      }
    }
  }
  // 32-way reduce tree, chunk = 8 pos x 16 = 128 floats
  float* buf = smem;
#pragma unroll
  for (int half = 16; half >= 1; half >>= 1) {
    __syncthreads();
    if (g >= half && g < 2 * half) {
      float* d = buf + (g - half) * 128 + p * 16;
#pragma unroll
      for (int j = 0; j < 4; ++j)
#pragma unroll
        for (int c = 0; c < 4; ++c) d[j * 4 + c] = acc[j][c];
    }
    __syncthreads();
    if (g < half) {
      const float* s = buf + g * 128 + p * 16;
#pragma unroll
      for (int j = 0; j < 4; ++j)
#pragma unroll
        for (int c = 0; c < 4; ++c) acc[j][c] += s[j * 4 + c];
    }
  }
  float* pb = buf + 2048;  // [8 oc][4 rows][4 cols]
  if (g == 0) {
#pragma unroll
    for (int j = 0; j < 4; ++j) {
      float bias = cb4[oc8 * 8 + ocg * 4 + j];
#pragma unroll
      for (int c = 0; c < 4; ++c) pb[(ocg * 4 + j) * 16 + row * 4 + c] = acc[j][c] + bias;
    }
  }
  __syncthreads();
  if (t < 32) {  // 2x2 pool -> emb
    int o = t >> 2, q = t & 3, py = q >> 1, px = q & 1;
    const float* b0 = pb + o * 16 + (2 * py) * 4 + 2 * px;
    float m = fmaxf(fmaxf(b0[0], b0[1]), fmaxf(b0[4], b0[5]));
    emb[b * 256 + (oc8 * 8 + o) * 4 + py * 2 + px] = m;
  }
}

// ---------------- K5a: MLP heads -> pc, log(pc), log1p(-pc), logcat ----------------
// grid (2 heads, 64 img), 256 threads
__global__ __launch_bounds__(256) void k_heads(const float* __restrict__ emb,
    const float* __restrict__ wc1, const float* __restrict__ bc1,
    const float* __restrict__ wc2, const float* __restrict__ bc2,
    const float* __restrict__ we1, const float* __restrict__ be1,
    const float* __restrict__ we2, const float* __restrict__ be2,
    float* __restrict__ pcw, float* __restrict__ lpcw,
    float* __restrict__ l1mw, float* __restrict__ lcatw) {
  int head = blockIdx.x, b = blockIdx.y;
  int t = threadIdx.x;
  __shared__ float e_s[256], h_s[256];
  __shared__ float aux;
  e_s[t] = emb[b * 256 + t];
  __syncthreads();
  const float* W1 = head ? we1 : wc1;
  const float* B1 = head ? be1 : bc1;
  float s = B1[t];
  for (int i = 0; i < 256; i += 4) {
    s = fmaf(e_s[i], W1[i * 256 + t], s);
    s = fmaf(e_s[i + 1], W1[(i + 1) * 256 + t], s);
    s = fmaf(e_s[i + 2], W1[(i + 2) * 256 + t], s);
    s = fmaf(e_s[i + 3], W1[(i + 3) * 256 + t], s);
  }
  h_s[t] = fmaxf(s, 0.f);
  __syncthreads();
  int NO = head ? 36 : 120;
  const float* W2 = head ? we2 : wc2;
  const float* B2 = head ? be2 : bc2;
  if (t < NO) {
    float s2 = B2[t];
    for (int i = 0; i < 256; ++i) s2 = fmaf(h_s[i], W2[i * NO + t], s2);
    float p = 1.f / (1.f + expf(-s2));
    p = fminf(fmaxf(p, EPSF), 1.f - EPSF);
    if (head == 0) {
      pcw[b * 120 + t] = p;
      lpcw[b * 120 + t] = logf(p);
      l1mw[b * 120 + t] = log1pf(-p);
    } else {
      e_s[t] = p;  // reuse as pe storage
    }
  }
  if (head == 1) {
    __syncthreads();
    if (t == 0) {
      float sm = 0.f;
      for (int j2 = 0; j2 < 36; ++j2) sm += e_s[j2];
      aux = sm;
    }
    __syncthreads();
    if (t < 36) lcatw[b * 36 + t] = logf(e_s[t] / aux);
  }
}

// ---------------- K5b: Monte-Carlo sampling + bitmask reachability + softmax ----------------
// grid 64 (img), 256 threads (1 thread = 1 sample)
__global__ __launch_bounds__(256) void k_mc(const float* __restrict__ enoise,
    const float* __restrict__ us, const float* __restrict__ ud,
    const int* __restrict__ edges,
    const float* __restrict__ pcw, const float* __restrict__ lpcw,
    const float* __restrict__ l1mw, const float* __restrict__ lcatw,
    float* __restrict__ out) {
  int b = blockIdx.x, t = threadIdx.x;
  __shared__ __align__(16) float pc_s[120];
  __shared__ __align__(16) float lpc_s[120];
  __shared__ __align__(16) float l1m_s[120];
  __shared__ __align__(16) float lcat_s[36];
  __shared__ __align__(16) int einfo[120];
  __shared__ float red_s[256];
  if (t < 120) {
    pc_s[t] = pcw[b * 120 + t];
    lpc_s[t] = lpcw[b * 120 + t];
    l1m_s[t] = l1mw[b * 120 + t];
    int u = edges[2 * t], v = edges[2 * t + 1];
    int d = v - u;
    int isV = (d == 6 || d == -6) ? 1 : 0;
    int pos = d > 0 ? u : v;
    einfo[t] = pos | (isV << 6);
  }
  if (t < 36) lcat_s[t] = lcatw[b * 36 + t];
  __syncthreads();

  float logw = 0.f;
  u64 H = 0, V = 0;
  {
    const float4* np = (const float4*)(enoise + ((size_t)(b * 256 + t)) * 120);
#pragma unroll
    for (int q = 0; q < 30; ++q) {
      float4 nz = np[q];
      float4 p4 = ((const float4*)pc_s)[q];
      float4 lp4 = ((const float4*)lpc_s)[q];
      float4 lm4 = ((const float4*)l1m_s)[q];
      int4 e4 = ((const int4*)einfo)[q];
      float nv[4] = {nz.x, nz.y, nz.z, nz.w};
      float pv[4] = {p4.x, p4.y, p4.z, p4.w};
      float lv[4] = {lp4.x, lp4.y, lp4.z, lp4.w};
      float mv[4] = {lm4.x, lm4.y, lm4.z, lm4.w};
      int ev[4] = {e4.x, e4.y, e4.z, e4.w};
#pragma unroll
      for (int r = 0; r < 4; ++r) {
        bool conn = nv[r] < pv[r];
        logw += conn ? lv[r] : mv[r];
        if (conn) {
          u64 bit = 1ull << (ev[r] & 63);
          if (ev[r] & 64) V |= bit; else H |= bit;
        }
      }
    }
  }
  int si = 0, di = 0;
  {
    const float4* up = (const float4*)(us + ((size_t)(b * 256 + t)) * 36);
    float best = -1e30f;
#pragma unroll
    for (int q = 0; q < 9; ++q) {
      float4 uv = up[q];
      float4 lc4 = ((const float4*)lcat_s)[q];
      float vv[4] = {uv.x, uv.y, uv.z, uv.w};
      float lc[4] = {lc4.x, lc4.y, lc4.z, lc4.w};
#pragma unroll
      for (int r = 0; r < 4; ++r) {
        float u = fminf(fmaxf(vv[r], EPSF), 1.f - EPSF);
        float gq = -logf(-logf(u));
        float val = lc[r] + gq;
        if (val > best) { best = val; si = q * 4 + r; }
      }
    }
  }
  {
    const float4* up = (const float4*)(ud + ((size_t)(b * 256 + t)) * 36);
    float best = -1e30f;
#pragma unroll
    for (int q = 0; q < 9; ++q) {
      float4 uv = up[q];
      float4 lc4 = ((const float4*)lcat_s)[q];
      float vv[4] = {uv.x, uv.y, uv.z, uv.w};
      float lc[4] = {lc4.x, lc4.y, lc4.z, lc4.w};
#pragma unroll
      for (int r = 0; r < 4; ++r) {
        float u = fminf(fmaxf(vv[r], EPSF), 1.f - EPSF);
        float gq = -logf(-logf(u));
        float val = lc[r] + gq;
        if (val > best) { best = val; di = q * 4 + r; }
      }
    }
  }
  logw += lcat_s[si] + lcat_s[di];

  u64 comp = 1ull << si;
  while (true) {
    u64 prev = comp;
    comp |= ((comp & H) << 1) | ((comp >> 1) & H);
    comp |= ((comp & V) << 6) | ((comp >> 6) & V);
    if (comp == prev) break;
  }
  float ex;
  if (si == di) ex = (comp != (1ull << si)) ? 1.f : 0.f;
  else ex = ((comp >> di) & 1ull) ? 1.f : 0.f;

  red_s[t] = logw; __syncthreads();
  for (int off = 128; off > 0; off >>= 1) {
    if (t < off) red_s[t] = fmaxf(red_s[t], red_s[t + off]);
    __syncthreads();
  }
  float m = red_s[0]; __syncthreads();
  float evx = expf(logw - m);
  red_s[t] = evx; __syncthreads();
  for (int off = 128; off > 0; off >>= 1) {
    if (t < off) red_s[t] += red_s[t + off];
    __syncthreads();
  }
  float den = red_s[0]; __syncthreads();
  red_s[t] = evx * ex; __syncthreads();
  for (int off = 128; off > 0; off >>= 1) {
    if (t < off) red_s[t] += red_s[t + off];
    __syncthreads();
  }
  if (t == 0) {
    float p1v = red_s[0] / den;
    out[b * 2] = 1.f - p1v;
    out[b * 2 + 1] = p1v;
  }
}

extern "C" void kernel_launch(void* const* d_in, const int* in_sizes, int n_in,
                              void* d_out, int out_size, void* d_ws, size_t ws_size,
                              hipStream_t stream) {
  const float* image = (const float*)d_in[0];
  const float* enoise = (const float*)d_in[1];
  const float* us = (const float*)d_in[2];
  const float* udn = (const float*)d_in[3];
  const float* cw1 = (const float*)d_in[4];
  const float* cb1 = (const float*)d_in[5];
  const float* cw2 = (const float*)d_in[6];
  const float* cb2 = (const float*)d_in[7];
  const float* cw3 = (const float*)d_in[8];
  const float* cb3 = (const float*)d_in[9];
  const float* cw4 = (const float*)d_in[10];
  const float* cb4 = (const float*)d_in[11];
  const float* wc1 = (const float*)d_in[12];
  const float* bc1 = (const float*)d_in[13];
  const float* wc2 = (const float*)d_in[14];
  const float* bc2 = (const float*)d_in[15];
  const float* we1 = (const float*)d_in[16];
  const float* be1 = (const float*)d_in[17];
  const float* we2 = (const float*)d_in[18];
  const float* be2 = (const float*)d_in[19];
  const int* edges = (const int*)d_in[20];

  float* ws = (float*)d_ws;
  float* c1 = ws;                  // 64*32*784
  float* p1w = ws + 1605632;       // 64*32*144
  float* c3 = ws + 1900544;        // 64*64*64
  float* emb = ws + 2162688;       // 64*256
  float* pcw = ws + 2179072;
  float* lpcw = ws + 2186752;
  float* l1mw = ws + 2194432;
  float* lcatw = ws + 2202112;
  float* outp = (float*)d_out;

  k_conv1<<<dim3(4, 64), dim3(512), 0, stream>>>(image, cw1, cb1, c1);
  k_conv2<<<dim3(4, 2, 64), dim3(384), 0, stream>>>(c1, cw2, cb2, p1w);
  k_conv3<<<dim3(8, 64), dim3(256), 0, stream>>>(p1w, cw3, cb3, c3);
  k_conv4<<<dim3(8, 64), dim3(256), 0, stream>>>(c3, cw4, cb4, emb);
  k_heads<<<dim3(2, 64), dim3(256), 0, stream>>>(emb, wc1, bc1, wc2, bc2,
                                                 we1, be1, we2, be2,
                                                 pcw, lpcw, l1mw, lcatw);
  k_mc<<<dim3(64), dim3(256), 0, stream>>>(enoise, us, udn, edges,
                                           pcw, lpcw, l1mw, lcatw, outp);
}

// Round 3
// 126.997 us; speedup vs baseline: 1.0648x; 1.0588x over previous
//
#include <hip/hip_runtime.h>

typedef unsigned long long u64;
#define EPSF 1e-6f

// ---------------- K1: conv1 1->32ch, 32x32 -> 28x28 ----------------
// grid (4 slabs of 8 oc, 64 img), 512 threads = (rowhalf:2) x (oc:8) x (x:32).
__global__ __launch_bounds__(512) void k_conv1(const float* __restrict__ img,
                                               const float* __restrict__ cw1,
                                               const float* __restrict__ cb1,
                                               float* __restrict__ c1) {
  int slab = blockIdx.x, b = blockIdx.y;
  __shared__ float simg[32 * 33];
  for (int k = threadIdx.x; k < 1024; k += 512) {
    int y = k >> 5, x = k & 31;
    simg[y * 33 + x] = img[b * 1024 + k];
  }
  int half = threadIdx.x >> 8;      // 0: out rows 0..13, 1: rows 14..27
  int u = threadIdx.x & 255;
  int ocl = u >> 5;
  int x = u & 31;
  int oc = slab * 8 + ocl;
  int y0 = half * 14;
  float w[25];
#pragma unroll
  for (int k = 0; k < 25; ++k) w[k] = cw1[oc * 25 + k];
  float bias = cb1[oc];
  __syncthreads();
  if (x < 28) {
    float acc[5];
#pragma unroll
    for (int k = 0; k < 5; ++k) acc[k] = bias;
    float* outp = c1 + (b * 32 + oc) * 784 + x;
#pragma unroll
    for (int rr = 0; rr < 18; ++rr) {
      int r = y0 + rr;
      float in[5];
#pragma unroll
      for (int c = 0; c < 5; ++c) in[c] = simg[r * 33 + x + c];
#pragma unroll
      for (int ky = 0; ky < 5; ++ky) {
        if (rr < ky || rr - ky > 13) continue;  // compile-time pruned
        int slot = (rr - ky) % 5;
#pragma unroll
        for (int kx = 0; kx < 5; ++kx)
          acc[slot] = fmaf(w[ky * 5 + kx], in[kx], acc[slot]);
      }
      if (rr >= 4) {
        int slot = (rr - 4) % 5;
        outp[(y0 + rr - 4) * 28] = acc[slot];
        acc[slot] = bias;
      }
    }
  }
}

// ---------------- K2: conv2 32->32ch, 28x28 -> 24x24, fused 2x2 maxpool -> 12x12 --------
// grid (4 ocq of 8 oc, 64 img) = 256 blocks, 512 threads = 8 waves.
// Stage the FULL input image (32ch x 28x28 = 100KB LDS) ONCE. Wave = one oc;
// weights via wave-uniform scalar loads (readfirstlane -> s_load). Lane owns a
// 3x3 output patch (64 lanes x 9 = 576 = 24x24). Only 2 barriers total.
__global__ __launch_bounds__(512) void k_conv2(const float* __restrict__ c1,
                                               const float* __restrict__ cw2,
                                               const float* __restrict__ cb2,
                                               float* __restrict__ p1w) {
  int ocq = blockIdx.x, b = blockIdx.y;
  __shared__ float smem[29696];     // 118.8 KB: sInp[25088] | pb[8*576]
  float* sInp = smem;               // [ic][28*28]
  float* pb = smem + 25088;         // [oc_local][24*24]
  int t = threadIdx.x;
  {  // stage whole image: 6272 float4
    const float4* src = (const float4*)(c1 + (size_t)b * 32 * 784);
    float4* dst = (float4*)sInp;
    for (int k = t; k < 6272; k += 512) dst[k] = src[k];
  }
  int w = __builtin_amdgcn_readfirstlane(t >> 6);   // wave id = local oc
  int l = t & 63;
  int py = l >> 3, px = l & 7;                      // 3x3 patch origin (3py, 3px)
  int oc = ocq * 8 + w;
  const float* wrow = cw2 + (size_t)oc * 800;       // SGPR base
  float acc[3][3];
#pragma unroll
  for (int i = 0; i < 3; ++i)
#pragma unroll
    for (int j = 0; j < 3; ++j) acc[i][j] = 0.f;
  __syncthreads();

  const float* base0 = sInp + 3 * py * 28 + 3 * px;
  for (int ic = 0; ic < 32; ++ic) {
    float w25[25];
    const float* wr = wrow + ic * 25;
#pragma unroll
    for (int k = 0; k < 25; ++k) w25[k] = wr[k];
    const float* base = base0 + ic * 784;
#pragma unroll
    for (int rr = 0; rr < 7; ++rr) {
      float win[7];
#pragma unroll
      for (int m = 0; m < 7; ++m) win[m] = base[rr * 28 + m];
#pragma unroll
      for (int i = 0; i < 3; ++i) {
        if (i > rr || rr - i > 4) continue;  // compile-time pruned
        int ky = rr - i;
#pragma unroll
        for (int kx = 0; kx < 5; ++kx) {
#pragma unroll
          for (int j = 0; j < 3; ++j)
            acc[i][j] = fmaf(w25[ky * 5 + kx], win[j + kx], acc[i][j]);
        }
      }
    }
  }
  // write conv result (+bias) to pool buffer
  float bias = cb2[oc];
  float* pbw = pb + w * 576 + 3 * py * 24 + 3 * px;
#pragma unroll
  for (int i = 0; i < 3; ++i)
#pragma unroll
    for (int j = 0; j < 3; ++j) pbw[i * 24 + j] = acc[i][j] + bias;
  __syncthreads();
  // fused 2x2 maxpool -> p1w[img][32][12][12]
  for (int k = t; k < 1152; k += 512) {
    int o = k / 144, rem = k % 144;
    int PY = rem / 12, PX = rem % 12;
    const float* b0 = pb + o * 576 + (2 * PY) * 24 + 2 * PX;
    float m = fmaxf(fmaxf(b0[0], b0[1]), fmaxf(b0[24], b0[25]));
    p1w[((size_t)b * 32 + ocq * 8 + o) * 144 + PY * 12 + PX] = m;
  }
}

// ---------------- K3: conv3 32->64ch, 12x12 -> 8x8 ----------------
// grid (8 groups of 8 oc, 64 img) = 512 blocks, 256 threads = g:16(2ic) x (ocg:2 x row:8).
__global__ __launch_bounds__(256) void k_conv3(const float* __restrict__ p1w,
                                               const float* __restrict__ cw3,
                                               const float* __restrict__ cb3,
                                               float* __restrict__ c3) {
  int oc8 = blockIdx.x, b = blockIdx.y;
  __shared__ float smem[11008];  // w3s 6400 | ins 4608 ; reduce aliases [0..4096)
  float* w3s = smem;
  float* ins = smem + 6400;
  int t = threadIdx.x;
  {
    const float4* src = (const float4*)(p1w + b * 32 * 144);
    float4* dst = (float4*)ins;
    for (int k = t; k < 1152; k += 256) dst[k] = src[k];
  }
  {
    const float4* src = (const float4*)(cw3 + oc8 * 8 * 800);
    for (int k4 = t; k4 < 1600; k4 += 256) {
      float4 v = src[k4];
      float vv[4] = {v.x, v.y, v.z, v.w};
      int k = k4 * 4;
#pragma unroll
      for (int r = 0; r < 4; ++r) {
        int kk = k + r;
        int o = kk / 800, rest = kk % 800;
        w3s[rest * 8 + o] = vv[r];
      }
    }
  }
  int g = t >> 4, p = t & 15;
  int ocg = p >> 3, row = p & 7;
  float acc[4][8];
#pragma unroll
  for (int j = 0; j < 4; ++j)
#pragma unroll
    for (int c = 0; c < 8; ++c) acc[j][c] = 0.f;
  __syncthreads();
#pragma unroll
  for (int icl = 0; icl < 2; ++icl) {
    int ic = g + icl * 16;
#pragma unroll
    for (int ky = 0; ky < 5; ++ky) {
      const float4* rp = (const float4*)(ins + ic * 144 + (row + ky) * 12);
      float win[12];
#pragma unroll
      for (int q = 0; q < 3; ++q) {
        float4 v = rp[q];
        win[4 * q] = v.x; win[4 * q + 1] = v.y; win[4 * q + 2] = v.z; win[4 * q + 3] = v.w;
      }
      const float* wb = w3s + (ic * 25 + ky * 5) * 8 + ocg * 4;
#pragma unroll
      for (int kx = 0; kx < 5; ++kx) {
        float wq[4];
        *(float4*)wq = *(const float4*)(wb + kx * 8);
#pragma unroll
        for (int c = 0; c < 8; ++c) {
#pragma unroll
          for (int j = 0; j < 4; ++j) acc[j][c] = fmaf(wq[j], win[c + kx], acc[j][c]);
        }
      }
    }
  }
  // 16-way reduce tree, chunk = 16 pos x 32 = 512 floats
  float* buf = smem;
  __syncthreads();
  if (g >= 8) {
    float* d = buf + (g - 8) * 512 + p * 32;
#pragma unroll
    for (int j = 0; j < 4; ++j)
#pragma unroll
      for (int c = 0; c < 8; ++c) d[j * 8 + c] = acc[j][c];
  }
  __syncthreads();
  if (g < 8) {
    const float* s = buf + g * 512 + p * 32;
#pragma unroll
    for (int j = 0; j < 4; ++j)
#pragma unroll
      for (int c = 0; c < 8; ++c) acc[j][c] += s[j * 8 + c];
  }
  __syncthreads();
  if (g >= 4 && g < 8) {
    float* d = buf + (g - 4) * 512 + p * 32;
#pragma unroll
    for (int j = 0; j < 4; ++j)
#pragma unroll
      for (int c = 0; c < 8; ++c) d[j * 8 + c] = acc[j][c];
  }
  __syncthreads();
  if (g < 4) {
    const float* s = buf + g * 512 + p * 32;
#pragma unroll
    for (int j = 0; j < 4; ++j)
#pragma unroll
      for (int c = 0; c < 8; ++c) acc[j][c] += s[j * 8 + c];
  }
  __syncthreads();
  if (g == 2 || g == 3) {
    float* d = buf + (g - 2) * 512 + p * 32;
#pragma unroll
    for (int j = 0; j < 4; ++j)
#pragma unroll
      for (int c = 0; c < 8; ++c) d[j * 8 + c] = acc[j][c];
  }
  __syncthreads();
  if (g < 2) {
    const float* s = buf + g * 512 + p * 32;
#pragma unroll
    for (int j = 0; j < 4; ++j)
#pragma unroll
      for (int c = 0; c < 8; ++c) acc[j][c] += s[j * 8 + c];
  }
  __syncthreads();
  if (g == 1) {
    float* d = buf + p * 32;
#pragma unroll
    for (int j = 0; j < 4; ++j)
#pragma unroll
      for (int c = 0; c < 8; ++c) d[j * 8 + c] = acc[j][c];
  }
  __syncthreads();
  if (g == 0) {
    const float* s = buf + p * 32;
#pragma unroll
    for (int j = 0; j < 4; ++j) {
      float bias = cb3[oc8 * 8 + ocg * 4 + j];
      float4 v0, v1;
      v0.x = acc[j][0] + s[j * 8 + 0] + bias; v0.y = acc[j][1] + s[j * 8 + 1] + bias;
      v0.z = acc[j][2] + s[j * 8 + 2] + bias; v0.w = acc[j][3] + s[j * 8 + 3] + bias;
      v1.x = acc[j][4] + s[j * 8 + 4] + bias; v1.y = acc[j][5] + s[j * 8 + 5] + bias;
      v1.z = acc[j][6] + s[j * 8 + 6] + bias; v1.w = acc[j][7] + s[j * 8 + 7] + bias;
      float* op = c3 + (b * 64 + oc8 * 8 + ocg * 4 + j) * 64 + row * 8;
      *(float4*)op = v0; *(float4*)(op + 4) = v1;
    }
  }
}

// ---------------- K4: conv4 64->64ch, 8x8 -> 4x4, fused pool -> emb[256] ----------------
// grid (8 groups of 8 oc, 64 img) = 512 blocks, 256 threads = g:32(2ic) x (ocg:2 x row:4).
__global__ __launch_bounds__(256) void k_conv4(const float* __restrict__ c3,
                                               const float* __restrict__ cw4,
                                               const float* __restrict__ cb4,
                                               float* __restrict__ emb) {
  int oc8 = blockIdx.x, b = blockIdx.y;
  __shared__ float smem[17152];  // w4s 12800 | ins 64*68 ; reduce aliases [0..2048), pb @2048
  float* w4s = smem;
  float* ins = smem + 12800;     // padded stride 68 per ic
  int t = threadIdx.x;
  {
    const float4* src = (const float4*)(c3 + b * 4096);
    for (int k = t; k < 1024; k += 256) {
      int ic = k >> 4, q = k & 15;
      *(float4*)(ins + ic * 68 + q * 4) = src[k];
    }
  }
  {
    const float4* src = (const float4*)(cw4 + oc8 * 8 * 1600);
    for (int k4 = t; k4 < 3200; k4 += 256) {
      float4 v = src[k4];
      float vv[4] = {v.x, v.y, v.z, v.w};
      int k = k4 * 4;
#pragma unroll
      for (int r = 0; r < 4; ++r) {
        int kk = k + r;
        int o = kk / 1600, rest = kk % 1600;
        w4s[rest * 8 + o] = vv[r];
      }
    }
  }
  int g = t >> 3, p = t & 7;
  int ocg = p >> 2, row = p & 3;
  float acc[4][4];
#pragma unroll
  for (int j = 0; j < 4; ++j)
#pragma unroll
    for (int c = 0; c < 4; ++c) acc[j][c] = 0.f;
  __syncthreads();
#pragma unroll
  for (int icl = 0; icl < 2; ++icl) {
    int ic = g + icl * 32;
#pragma unroll
    for (int ky = 0; ky < 5; ++ky) {
      const float4* rp = (const float4*)(ins + ic * 68 + (row + ky) * 8);
      float win[8];
#pragma unroll
      for (int q = 0; q < 2; ++q) {
        float4 v = rp[q];
        win[4 * q] = v.x; win[4 * q + 1] = v.y; win[4 * q + 2] = v.z; win[4 * q + 3] = v.w;
      }
      const float* wb = w4s + (ic * 25 + ky * 5) * 8 + ocg * 4;
#pragma unroll
      for (int kx = 0; kx < 5; ++kx) {
        float wq[4];
        *(float4*)wq = *(const float4*)(wb + kx * 8);
#pragma unroll
        for (int c = 0; c < 4; ++c) {
#pragma unroll
          for (int j = 0; j < 4; ++j) acc[j][c] = fmaf(wq[j], win[c + kx], acc[j][c]);
        }
      }
    }
  }
  // 32-way reduce tree, chunk = 8 pos x 16 = 128 floats
  float* buf = smem;
#pragma unroll
  for (int half = 16; half >= 1; half >>= 1) {
    __syncthreads();
    if (g >= half && g < 2 * half) {
      float* d = buf + (g - half) * 128 + p * 16;
#pragma unroll
      for (int j = 0; j < 4; ++j)
#pragma unroll
        for (int c = 0; c < 4; ++c) d[j * 4 + c] = acc[j][c];
    }
    __syncthreads();
    if (g < half) {
      const float* s = buf + g * 128 + p * 16;
#pragma unroll
      for (int j = 0; j < 4; ++j)
#pragma unroll
        for (int c = 0; c < 4; ++c) acc[j][c] += s[j * 4 + c];
    }
  }
  float* pb = buf + 2048;  // [8 oc][4 rows][4 cols]
  if (g == 0) {
#pragma unroll
    for (int j = 0; j < 4; ++j) {
      float bias = cb4[oc8 * 8 + ocg * 4 + j];
#pragma unroll
      for (int c = 0; c < 4; ++c) pb[(ocg * 4 + j) * 16 + row * 4 + c] = acc[j][c] + bias;
    }
  }
  __syncthreads();
  if (t < 32) {  // 2x2 pool -> emb
    int o = t >> 2, q = t & 3, py = q >> 1, px = q & 1;
    const float* b0 = pb + o * 16 + (2 * py) * 4 + 2 * px;
    float m = fmaxf(fmaxf(b0[0], b0[1]), fmaxf(b0[4], b0[5]));
    emb[b * 256 + (oc8 * 8 + o) * 4 + py * 2 + px] = m;
  }
}

// ---------------- K5a: MLP heads -> pc, log(pc), log1p(-pc), logcat ----------------
// grid (2 heads, 64 img), 256 threads
__global__ __launch_bounds__(256) void k_heads(const float* __restrict__ emb,
    const float* __restrict__ wc1, const float* __restrict__ bc1,
    const float* __restrict__ wc2, const float* __restrict__ bc2,
    const float* __restrict__ we1, const float* __restrict__ be1,
    const float* __restrict__ we2, const float* __restrict__ be2,
    float* __restrict__ pcw, float* __restrict__ lpcw,
    float* __restrict__ l1mw, float* __restrict__ lcatw) {
  int head = blockIdx.x, b = blockIdx.y;
  int t = threadIdx.x;
  __shared__ float e_s[256], h_s[256];
  __shared__ float aux;
  e_s[t] = emb[b * 256 + t];
  __syncthreads();
  const float* W1 = head ? we1 : wc1;
  const float* B1 = head ? be1 : bc1;
  float s = B1[t];
  for (int i = 0; i < 256; i += 4) {
    s = fmaf(e_s[i], W1[i * 256 + t], s);
    s = fmaf(e_s[i + 1], W1[(i + 1) * 256 + t], s);
    s = fmaf(e_s[i + 2], W1[(i + 2) * 256 + t], s);
    s = fmaf(e_s[i + 3], W1[(i + 3) * 256 + t], s);
  }
  h_s[t] = fmaxf(s, 0.f);
  __syncthreads();
  int NO = head ? 36 : 120;
  const float* W2 = head ? we2 : wc2;
  const float* B2 = head ? be2 : bc2;
  if (t < NO) {
    float s2 = B2[t];
    for (int i = 0; i < 256; ++i) s2 = fmaf(h_s[i], W2[i * NO + t], s2);
    float p = 1.f / (1.f + expf(-s2));
    p = fminf(fmaxf(p, EPSF), 1.f - EPSF);
    if (head == 0) {
      pcw[b * 120 + t] = p;
      lpcw[b * 120 + t] = logf(p);
      l1mw[b * 120 + t] = log1pf(-p);
    } else {
      e_s[t] = p;  // reuse as pe storage
    }
  }
  if (head == 1) {
    __syncthreads();
    if (t == 0) {
      float sm = 0.f;
      for (int j2 = 0; j2 < 36; ++j2) sm += e_s[j2];
      aux = sm;
    }
    __syncthreads();
    if (t < 36) lcatw[b * 36 + t] = logf(e_s[t] / aux);
  }
}

// ---------------- K5b: Monte-Carlo sampling + bitmask reachability + softmax ----------------
// grid 64 (img), 256 threads (1 thread = 1 sample)
__global__ __launch_bounds__(256) void k_mc(const float* __restrict__ enoise,
    const float* __restrict__ us, const float* __restrict__ ud,
    const int* __restrict__ edges,
    const float* __restrict__ pcw, const float* __restrict__ lpcw,
    const float* __restrict__ l1mw, const float* __restrict__ lcatw,
    float* __restrict__ out) {
  int b = blockIdx.x, t = threadIdx.x;
  __shared__ __align__(16) float pc_s[120];
  __shared__ __align__(16) float lpc_s[120];
  __shared__ __align__(16) float l1m_s[120];
  __shared__ __align__(16) float lcat_s[36];
  __shared__ __align__(16) int einfo[120];
  __shared__ float red_s[256];
  if (t < 120) {
    pc_s[t] = pcw[b * 120 + t];
    lpc_s[t] = lpcw[b * 120 + t];
    l1m_s[t] = l1mw[b * 120 + t];
    int u = edges[2 * t], v = edges[2 * t + 1];
    int d = v - u;
    int isV = (d == 6 || d == -6) ? 1 : 0;
    int pos = d > 0 ? u : v;
    einfo[t] = pos | (isV << 6);
  }
  if (t < 36) lcat_s[t] = lcatw[b * 36 + t];
  __syncthreads();

  float logw = 0.f;
  u64 H = 0, V = 0;
  {
    const float4* np = (const float4*)(enoise + ((size_t)(b * 256 + t)) * 120);
#pragma unroll
    for (int q = 0; q < 30; ++q) {
      float4 nz = np[q];
      float4 p4 = ((const float4*)pc_s)[q];
      float4 lp4 = ((const float4*)lpc_s)[q];
      float4 lm4 = ((const float4*)l1m_s)[q];
      int4 e4 = ((const int4*)einfo)[q];
      float nv[4] = {nz.x, nz.y, nz.z, nz.w};
      float pv[4] = {p4.x, p4.y, p4.z, p4.w};
      float lv[4] = {lp4.x, lp4.y, lp4.z, lp4.w};
      float mv[4] = {lm4.x, lm4.y, lm4.z, lm4.w};
      int ev[4] = {e4.x, e4.y, e4.z, e4.w};
#pragma unroll
      for (int r = 0; r < 4; ++r) {
        bool conn = nv[r] < pv[r];
        logw += conn ? lv[r] : mv[r];
        if (conn) {
          u64 bit = 1ull << (ev[r] & 63);
          if (ev[r] & 64) V |= bit; else H |= bit;
        }
      }
    }
  }
  int si = 0, di = 0;
  {
    const float4* up = (const float4*)(us + ((size_t)(b * 256 + t)) * 36);
    float best = -1e30f;
#pragma unroll
    for (int q = 0; q < 9; ++q) {
      float4 uv = up[q];
      float4 lc4 = ((const float4*)lcat_s)[q];
      float vv[4] = {uv.x, uv.y, uv.z, uv.w};
      float lc[4] = {lc4.x, lc4.y, lc4.z, lc4.w};
#pragma unroll
      for (int r = 0; r < 4; ++r) {
        float u = fminf(fmaxf(vv[r], EPSF), 1.f - EPSF);
        float gq = -logf(-logf(u));
        float val = lc[r] + gq;
        if (val > best) { best = val; si = q * 4 + r; }
      }
    }
  }
  {
    const float4* up = (const float4*)(ud + ((size_t)(b * 256 + t)) * 36);
    float best = -1e30f;
#pragma unroll
    for (int q = 0; q < 9; ++q) {
      float4 uv = up[q];
      float4 lc4 = ((const float4*)lcat_s)[q];
      float vv[4] = {uv.x, uv.y, uv.z, uv.w};
      float lc[4] = {lc4.x, lc4.y, lc4.z, lc4.w};
#pragma unroll
      for (int r = 0; r < 4; ++r) {
        float u = fminf(fmaxf(vv[r], EPSF), 1.f - EPSF);
        float gq = -logf(-logf(u));
        float val = lc[r] + gq;
        if (val > best) { best = val; di = q * 4 + r; }
      }
    }
  }
  logw += lcat_s[si] + lcat_s[di];

  u64 comp = 1ull << si;
  while (true) {
    u64 prev = comp;
    comp |= ((comp & H) << 1) | ((comp >> 1) & H);
    comp |= ((comp & V) << 6) | ((comp >> 6) & V);
    if (comp == prev) break;
  }
  float ex;
  if (si == di) ex = (comp != (1ull << si)) ? 1.f : 0.f;
  else ex = ((comp >> di) & 1ull) ? 1.f : 0.f;

  red_s[t] = logw; __syncthreads();
  for (int off = 128; off > 0; off >>= 1) {
    if (t < off) red_s[t] = fmaxf(red_s[t], red_s[t + off]);
    __syncthreads();
  }
  float m = red_s[0]; __syncthreads();
  float evx = expf(logw - m);
  red_s[t] = evx; __syncthreads();
  for (int off = 128; off > 0; off >>= 1) {
    if (t < off) red_s[t] += red_s[t + off];
    __syncthreads();
  }
  float den = red_s[0]; __syncthreads();
  red_s[t] = evx * ex; __syncthreads();
  for (int off = 128; off > 0; off >>= 1) {
    if (t < off) red_s[t] += red_s[t + off];
    __syncthreads();
  }
  if (t == 0) {
    float p1v = red_s[0] / den;
    out[b * 2] = 1.f - p1v;
    out[b * 2 + 1] = p1v;
  }
}

extern "C" void kernel_launch(void* const* d_in, const int* in_sizes, int n_in,
                              void* d_out, int out_size, void* d_ws, size_t ws_size,
                              hipStream_t stream) {
  const float* image = (const float*)d_in[0];
  const float* enoise = (const float*)d_in[1];
  const float* us = (const float*)d_in[2];
  const float* udn = (const float*)d_in[3];
  const float* cw1 = (const float*)d_in[4];
  const float* cb1 = (const float*)d_in[5];
  const float* cw2 = (const float*)d_in[6];
  const float* cb2 = (const float*)d_in[7];
  const float* cw3 = (const float*)d_in[8];
  const float* cb3 = (const float*)d_in[9];
  const float* cw4 = (const float*)d_in[10];
  const float* cb4 = (const float*)d_in[11];
  const float* wc1 = (const float*)d_in[12];
  const float* bc1 = (const float*)d_in[13];
  const float* wc2 = (const float*)d_in[14];
  const float* bc2 = (const float*)d_in[15];
  const float* we1 = (const float*)d_in[16];
  const float* be1 = (const float*)d_in[17];
  const float* we2 = (const float*)d_in[18];
  const float* be2 = (const float*)d_in[19];
  const int* edges = (const int*)d_in[20];

  float* ws = (float*)d_ws;
  float* c1 = ws;                  // 64*32*784
  float* p1w = ws + 1605632;       // 64*32*144
  float* c3 = ws + 1900544;        // 64*64*64
  float* emb = ws + 2162688;       // 64*256
  float* pcw = ws + 2179072;
  float* lpcw = ws + 2186752;
  float* l1mw = ws + 2194432;
  float* lcatw = ws + 2202112;
  float* outp = (float*)d_out;

  k_conv1<<<dim3(4, 64), dim3(512), 0, stream>>>(image, cw1, cb1, c1);
  k_conv2<<<dim3(4, 64), dim3(512), 0, stream>>>(c1, cw2, cb2, p1w);
  k_conv3<<<dim3(8, 64), dim3(256), 0, stream>>>(p1w, cw3, cb3, c3);
  k_conv4<<<dim3(8, 64), dim3(256), 0, stream>>>(c3, cw4, cb4, emb);
  k_heads<<<dim3(2, 64), dim3(256), 0, stream>>>(emb, wc1, bc1, wc2, bc2,
                                                 we1, be1, we2, be2,
                                                 pcw, lpcw, l1mw, lcatw);
  k_mc<<<dim3(64), dim3(256), 0, stream>>>(enoise, us, udn, edges,
                                           pcw, lpcw, l1mw, lcatw, outp);
}

// Round 5
// 126.918 us; speedup vs baseline: 1.0655x; 1.0006x over previous
//
#include <hip/hip_runtime.h>

typedef unsigned long long u64;
#define EPSF 1e-6f

// ---------------- K1: conv1 1->32ch, 32x32 -> 28x28 ----------------
// grid (4 slabs of 8 oc, 64 img), 512 threads = (rowhalf:2) x (oc:8) x (x:32).
__global__ __launch_bounds__(512) void k_conv1(const float* __restrict__ img,
                                               const float* __restrict__ cw1,
                                               const float* __restrict__ cb1,
                                               float* __restrict__ c1) {
  int slab = blockIdx.x, b = blockIdx.y;
  __shared__ float simg[32 * 33];
  for (int k = threadIdx.x; k < 1024; k += 512) {
    int y = k >> 5, x = k & 31;
    simg[y * 33 + x] = img[b * 1024 + k];
  }
  int half = threadIdx.x >> 8;      // 0: out rows 0..13, 1: rows 14..27
  int u = threadIdx.x & 255;
  int ocl = u >> 5;
  int x = u & 31;
  int oc = slab * 8 + ocl;
  int y0 = half * 14;
  float w[25];
#pragma unroll
  for (int k = 0; k < 25; ++k) w[k] = cw1[oc * 25 + k];
  float bias = cb1[oc];
  __syncthreads();
  if (x < 28) {
    float acc[5];
#pragma unroll
    for (int k = 0; k < 5; ++k) acc[k] = bias;
    float* outp = c1 + (b * 32 + oc) * 784 + x;
#pragma unroll
    for (int rr = 0; rr < 18; ++rr) {
      int r = y0 + rr;
      float in[5];
#pragma unroll
      for (int c = 0; c < 5; ++c) in[c] = simg[r * 33 + x + c];
#pragma unroll
      for (int ky = 0; ky < 5; ++ky) {
        if (rr < ky || rr - ky > 13) continue;  // compile-time pruned
        int slot = (rr - ky) % 5;
#pragma unroll
        for (int kx = 0; kx < 5; ++kx)
          acc[slot] = fmaf(w[ky * 5 + kx], in[kx], acc[slot]);
      }
      if (rr >= 4) {
        int slot = (rr - 4) % 5;
        outp[(y0 + rr - 4) * 28] = acc[slot];
        acc[slot] = bias;
      }
    }
  }
}

// ---------------- K2: conv2 32->32ch, 28x28 -> 24x24, fused 2x2 maxpool -> 12x12 --------
// grid (4 ocq of 8 oc, 64 img) = 256 blocks, 1024 threads = 16 waves (4/SIMD).
// Full input image staged once (32ch x 784 = 100KB LDS). Wave = (oc = w&7,
// ic-half = w>>3). Weights via wave-uniform scalar loads, double-buffered.
// Lane owns a 3x3 output patch (64 lanes x 9 = 576 = 24x24).
__global__ __launch_bounds__(1024) void k_conv2(const float* __restrict__ c1,
                                                const float* __restrict__ cw2,
                                                const float* __restrict__ cb2,
                                                float* __restrict__ p1w) {
  int ocq = blockIdx.x, b = blockIdx.y;
  __shared__ float smem[25088];     // 100.4 KB: sInp[32][784]; later aliased:
  float* sInp = smem;               //   red[8][576] @0, cb[8][576] @4608
  int t = threadIdx.x;
  {  // stage whole image: 6272 float4
    const float4* src = (const float4*)(c1 + (size_t)b * 32 * 784);
    float4* dst = (float4*)sInp;
    for (int k = t; k < 6272; k += 1024) dst[k] = src[k];
  }
  int w = __builtin_amdgcn_readfirstlane(t >> 6);   // wave id
  int ocl = w & 7;                                  // local oc
  int ich = w >> 3;                                 // ic half: 0 or 1
  int l = t & 63;
  int py = l >> 3, px = l & 7;                      // 3x3 patch origin (3py, 3px)
  int oc = ocq * 8 + ocl;
  const float* wrow = cw2 + (size_t)oc * 800 + ich * 16 * 25;  // SGPR base
  float acc[3][3];
#pragma unroll
  for (int i = 0; i < 3; ++i)
#pragma unroll
    for (int j = 0; j < 3; ++j) acc[i][j] = 0.f;
  __syncthreads();

  const float* base0 = sInp + (size_t)ich * 16 * 784 + 3 * py * 28 + 3 * px;

  float wA[25], wB[25];
#pragma unroll
  for (int k = 0; k < 25; ++k) wA[k] = wrow[k];

#define CONV2_IC(ICL, WREG)                                                  \
  {                                                                          \
    const float* base = base0 + (ICL) * 784;                                 \
    _Pragma("unroll") for (int rr = 0; rr < 7; ++rr) {                       \
      float win[7];                                                          \
      _Pragma("unroll") for (int m = 0; m < 7; ++m) win[m] = base[rr * 28 + m]; \
      _Pragma("unroll") for (int i = 0; i < 3; ++i) {                        \
        if (i > rr || rr - i > 4) continue;                                  \
        int ky = rr - i;                                                     \
        _Pragma("unroll") for (int kx = 0; kx < 5; ++kx) {                   \
          _Pragma("unroll") for (int j = 0; j < 3; ++j)                      \
            acc[i][j] = fmaf(WREG[ky * 5 + kx], win[j + kx], acc[i][j]);     \
        }                                                                    \
      }                                                                      \
    }                                                                        \
  }

#pragma unroll
  for (int icp = 0; icp < 8; ++icp) {
#pragma unroll
    for (int k = 0; k < 25; ++k) wB[k] = wrow[(2 * icp + 1) * 25 + k];
    CONV2_IC(2 * icp, wA)
    if (icp < 7) {
#pragma unroll
      for (int k = 0; k < 25; ++k) wA[k] = wrow[(2 * icp + 2) * 25 + k];
    }
    CONV2_IC(2 * icp + 1, wB)
  }
#undef CONV2_IC

  __syncthreads();   // all compute done; image buffer now dead, safe to alias
  float* red = smem;            // [8][576] partial sums from ic-half 1
  float* cb = smem + 4608;      // [8][576] final conv (+bias)
  if (ich == 1) {
    float* d = red + ocl * 576 + 3 * py * 24 + 3 * px;
#pragma unroll
    for (int i = 0; i < 3; ++i)
#pragma unroll
      for (int j = 0; j < 3; ++j) d[i * 24 + j] = acc[i][j];
  }
  __syncthreads();
  if (ich == 0) {
    float bias = cb2[oc];
    const float* s = red + ocl * 576 + 3 * py * 24 + 3 * px;
    float* d = cb + ocl * 576 + 3 * py * 24 + 3 * px;
#pragma unroll
    for (int i = 0; i < 3; ++i)
#pragma unroll
      for (int j = 0; j < 3; ++j) d[i * 24 + j] = acc[i][j] + s[i * 24 + j] + bias;
  }
  __syncthreads();
  // fused 2x2 maxpool -> p1w[img][32][12][12]  (1152 outputs, 1024 threads -> strided)
  for (int k = t; k < 1152; k += 1024) {
    int o = k / 144, rem = k % 144;
    int PY = rem / 12, PX = rem % 12;
    const float* b0 = cb + o * 576 + (2 * PY) * 24 + 2 * PX;
    float m = fmaxf(fmaxf(b0[0], b0[1]), fmaxf(b0[24], b0[25]));
    p1w[((size_t)b * 32 + ocq * 8 + o) * 144 + PY * 12 + PX] = m;
  }
}

// ---------------- K3: conv3 32->64ch, 12x12 -> 8x8 ----------------
// grid (8 groups of 8 oc, 64 img) = 512 blocks, 256 threads = g:16(2ic) x (ocg:2 x row:8).
__global__ __launch_bounds__(256) void k_conv3(const float* __restrict__ p1w,
                                               const float* __restrict__ cw3,
                                               const float* __restrict__ cb3,
                                               float* __restrict__ c3) {
  int oc8 = blockIdx.x, b = blockIdx.y;
  __shared__ float smem[11008];  // w3s 6400 | ins 4608 ; reduce aliases [0..4096)
  float* w3s = smem;
  float* ins = smem + 6400;
  int t = threadIdx.x;
  {
    const float4* src = (const float4*)(p1w + b * 32 * 144);
    float4* dst = (float4*)ins;
    for (int k = t; k < 1152; k += 256) dst[k] = src[k];
  }
  {
    const float4* src = (const float4*)(cw3 + oc8 * 8 * 800);
    for (int k4 = t; k4 < 1600; k4 += 256) {
      float4 v = src[k4];
      float vv[4] = {v.x, v.y, v.z, v.w};
      int k = k4 * 4;
#pragma unroll
      for (int r = 0; r < 4; ++r) {
        int kk = k + r;
        int o = kk / 800, rest = kk % 800;
        w3s[rest * 8 + o] = vv[r];
      }
    }
  }
  int g = t >> 4, p = t & 15;
  int ocg = p >> 3, row = p & 7;
  float acc[4][8];
#pragma unroll
  for (int j = 0; j < 4; ++j)
#pragma unroll
    for (int c = 0; c < 8; ++c) acc[j][c] = 0.f;
  __syncthreads();
#pragma unroll
  for (int icl = 0; icl < 2; ++icl) {
    int ic = g + icl * 16;
#pragma unroll
    for (int ky = 0; ky < 5; ++ky) {
      const float4* rp = (const float4*)(ins + ic * 144 + (row + ky) * 12);
      float win[12];
#pragma unroll
      for (int q = 0; q < 3; ++q) {
        float4 v = rp[q];
        win[4 * q] = v.x; win[4 * q + 1] = v.y; win[4 * q + 2] = v.z; win[4 * q + 3] = v.w;
      }
      const float* wb = w3s + (ic * 25 + ky * 5) * 8 + ocg * 4;
#pragma unroll
      for (int kx = 0; kx < 5; ++kx) {
        float wq[4];
        *(float4*)wq = *(const float4*)(wb + kx * 8);
#pragma unroll
        for (int c = 0; c < 8; ++c) {
#pragma unroll
          for (int j = 0; j < 4; ++j) acc[j][c] = fmaf(wq[j], win[c + kx], acc[j][c]);
        }
      }
    }
  }
  // 16-way reduce tree, chunk = 16 pos x 32 = 512 floats
  float* buf = smem;
  __syncthreads();
  if (g >= 8) {
    float* d = buf + (g - 8) * 512 + p * 32;
#pragma unroll
    for (int j = 0; j < 4; ++j)
#pragma unroll
      for (int c = 0; c < 8; ++c) d[j * 8 + c] = acc[j][c];
  }
  __syncthreads();
  if (g < 8) {
    const float* s = buf + g * 512 + p * 32;
#pragma unroll
    for (int j = 0; j < 4; ++j)
#pragma unroll
      for (int c = 0; c < 8; ++c) acc[j][c] += s[j * 8 + c];
  }
  __syncthreads();
  if (g >= 4 && g < 8) {
    float* d = buf + (g - 4) * 512 + p * 32;
#pragma unroll
    for (int j = 0; j < 4; ++j)
#pragma unroll
      for (int c = 0; c < 8; ++c) d[j * 8 + c] = acc[j][c];
  }
  __syncthreads();
  if (g < 4) {
    const float* s = buf + g * 512 + p * 32;
#pragma unroll
    for (int j = 0; j < 4; ++j)
#pragma unroll
      for (int c = 0; c < 8; ++c) acc[j][c] += s[j * 8 + c];
  }
  __syncthreads();
  if (g == 2 || g == 3) {
    float* d = buf + (g - 2) * 512 + p * 32;
#pragma unroll
    for (int j = 0; j < 4; ++j)
#pragma unroll
      for (int c = 0; c < 8; ++c) d[j * 8 + c] = acc[j][c];
  }
  __syncthreads();
  if (g < 2) {
    const float* s = buf + g * 512 + p * 32;
#pragma unroll
    for (int j = 0; j < 4; ++j)
#pragma unroll
      for (int c = 0; c < 8; ++c) acc[j][c] += s[j * 8 + c];
  }
  __syncthreads();
  if (g == 1) {
    float* d = buf + p * 32;
#pragma unroll
    for (int j = 0; j < 4; ++j)
#pragma unroll
      for (int c = 0; c < 8; ++c) d[j * 8 + c] = acc[j][c];
  }
  __syncthreads();
  if (g == 0) {
    const float* s = buf + p * 32;
#pragma unroll
    for (int j = 0; j < 4; ++j) {
      float bias = cb3[oc8 * 8 + ocg * 4 + j];
      float4 v0, v1;
      v0.x = acc[j][0] + s[j * 8 + 0] + bias; v0.y = acc[j][1] + s[j * 8 + 1] + bias;
      v0.z = acc[j][2] + s[j * 8 + 2] + bias; v0.w = acc[j][3] + s[j * 8 + 3] + bias;
      v1.x = acc[j][4] + s[j * 8 + 4] + bias; v1.y = acc[j][5] + s[j * 8 + 5] + bias;
      v1.z = acc[j][6] + s[j * 8 + 6] + bias; v1.w = acc[j][7] + s[j * 8 + 7] + bias;
      float* op = c3 + (b * 64 + oc8 * 8 + ocg * 4 + j) * 64 + row * 8;
      *(float4*)op = v0; *(float4*)(op + 4) = v1;
    }
  }
}

// ---------------- K4: conv4 64->64ch, 8x8 -> 4x4, fused pool -> emb[256] ----------------
// grid (8 groups of 8 oc, 64 img) = 512 blocks, 256 threads = g:32(2ic) x (ocg:2 x row:4).
__global__ __launch_bounds__(256) void k_conv4(const float* __restrict__ c3,
                                               const float* __restrict__ cw4,
                                               const float* __restrict__ cb4,
                                               float* __restrict__ emb) {
  int oc8 = blockIdx.x, b = blockIdx.y;
  __shared__ float smem[17152];  // w4s 12800 | ins 64*68 ; reduce aliases [0..2048), pb @2048
  float* w4s = smem;
  float* ins = smem + 12800;     // padded stride 68 per ic
  int t = threadIdx.x;
  {
    const float4* src = (const float4*)(c3 + b * 4096);
    for (int k = t; k < 1024; k += 256) {
      int ic = k >> 4, q = k & 15;
      *(float4*)(ins + ic * 68 + q * 4) = src[k];
    }
  }
  {
    const float4* src = (const float4*)(cw4 + oc8 * 8 * 1600);
    for (int k4 = t; k4 < 3200; k4 += 256) {
      float4 v = src[k4];
      float vv[4] = {v.x, v.y, v.z, v.w};
      int k = k4 * 4;
#pragma unroll
      for (int r = 0; r < 4; ++r) {
        int kk = k + r;
        int o = kk / 1600, rest = kk % 1600;
        w4s[rest * 8 + o] = vv[r];
      }
    }
  }
  int g = t >> 3, p = t & 7;
  int ocg = p >> 2, row = p & 3;
  float acc[4][4];
#pragma unroll
  for (int j = 0; j < 4; ++j)
#pragma unroll
    for (int c = 0; c < 4; ++c) acc[j][c] = 0.f;
  __syncthreads();
#pragma unroll
  for (int icl = 0; icl < 2; ++icl) {
    int ic = g + icl * 32;
#pragma unroll
    for (int ky = 0; ky < 5; ++ky) {
      const float4* rp = (const float4*)(ins + ic * 68 + (row + ky) * 8);
      float win[8];
#pragma unroll
      for (int q = 0; q < 2; ++q) {
        float4 v = rp[q];
        win[4 * q] = v.x; win[4 * q + 1] = v.y; win[4 * q + 2] = v.z; win[4 * q + 3] = v.w;
      }
      const float* wb = w4s + (ic * 25 + ky * 5) * 8 + ocg * 4;
#pragma unroll
      for (int kx = 0; kx < 5; ++kx) {
        float wq[4];
        *(float4*)wq = *(const float4*)(wb + kx * 8);
#pragma unroll
        for (int c = 0; c < 4; ++c) {
#pragma unroll
          for (int j = 0; j < 4; ++j) acc[j][c] = fmaf(wq[j], win[c + kx], acc[j][c]);
        }
      }
    }
  }
  // 32-way reduce tree, chunk = 8 pos x 16 = 128 floats
  float* buf = smem;
#pragma unroll
  for (int half = 16; half >= 1; half >>= 1) {
    __syncthreads();
    if (g >= half && g < 2 * half) {
      float* d = buf + (g - half) * 128 + p * 16;
#pragma unroll
      for (int j = 0; j < 4; ++j)
#pragma unroll
        for (int c = 0; c < 4; ++c) d[j * 4 + c] = acc[j][c];
    }
    __syncthreads();
    if (g < half) {
      const float* s = buf + g * 128 + p * 16;
#pragma unroll
      for (int j = 0; j < 4; ++j)
#pragma unroll
        for (int c = 0; c < 4; ++c) acc[j][c] += s[j * 4 + c];
    }
  }
  float* pb = buf + 2048;  // [8 oc][4 rows][4 cols]
  if (g == 0) {
#pragma unroll
    for (int j = 0; j < 4; ++j) {
      float bias = cb4[oc8 * 8 + ocg * 4 + j];
#pragma unroll
      for (int c = 0; c < 4; ++c) pb[(ocg * 4 + j) * 16 + row * 4 + c] = acc[j][c] + bias;
    }
  }
  __syncthreads();
  if (t < 32) {  // 2x2 pool -> emb
    int o = t >> 2, q = t & 3, py = q >> 1, px = q & 1;
    const float* b0 = pb + o * 16 + (2 * py) * 4 + 2 * px;
    float m = fmaxf(fmaxf(b0[0], b0[1]), fmaxf(b0[4], b0[5]));
    emb[b * 256 + (oc8 * 8 + o) * 4 + py * 2 + px] = m;
  }
}

// ---------------- K5a: MLP heads -> pc, log(pc), log1p(-pc), logcat ----------------
// grid (2 heads, 64 img), 256 threads
__global__ __launch_bounds__(256) void k_heads(const float* __restrict__ emb,
    const float* __restrict__ wc1, const float* __restrict__ bc1,
    const float* __restrict__ wc2, const float* __restrict__ bc2,
    const float* __restrict__ we1, const float* __restrict__ be1,
    const float* __restrict__ we2, const float* __restrict__ be2,
    float* __restrict__ pcw, float* __restrict__ lpcw,
    float* __restrict__ l1mw, float* __restrict__ lcatw) {
  int head = blockIdx.x, b = blockIdx.y;
  int t = threadIdx.x;
  __shared__ float e_s[256], h_s[256];
  __shared__ float aux;
  e_s[t] = emb[b * 256 + t];
  __syncthreads();
  const float* W1 = head ? we1 : wc1;
  const float* B1 = head ? be1 : bc1;
  float s = B1[t];
  for (int i = 0; i < 256; i += 4) {
    s = fmaf(e_s[i], W1[i * 256 + t], s);
    s = fmaf(e_s[i + 1], W1[(i + 1) * 256 + t], s);
    s = fmaf(e_s[i + 2], W1[(i + 2) * 256 + t], s);
    s = fmaf(e_s[i + 3], W1[(i + 3) * 256 + t], s);
  }
  h_s[t] = fmaxf(s, 0.f);
  __syncthreads();
  int NO = head ? 36 : 120;
  const float* W2 = head ? we2 : wc2;
  const float* B2 = head ? be2 : bc2;
  if (t < NO) {
    float s2 = B2[t];
    for (int i = 0; i < 256; ++i) s2 = fmaf(h_s[i], W2[i * NO + t], s2);
    float p = 1.f / (1.f + expf(-s2));
    p = fminf(fmaxf(p, EPSF), 1.f - EPSF);
    if (head == 0) {
      pcw[b * 120 + t] = p;
      lpcw[b * 120 + t] = logf(p);
      l1mw[b * 120 + t] = log1pf(-p);
    } else {
      e_s[t] = p;  // reuse as pe storage
    }
  }
  if (head == 1) {
    __syncthreads();
    if (t == 0) {
      float sm = 0.f;
      for (int j2 = 0; j2 < 36; ++j2) sm += e_s[j2];
      aux = sm;
    }
    __syncthreads();
    if (t < 36) lcatw[b * 36 + t] = logf(e_s[t] / aux);
  }
}

// ---------------- K5b: Monte-Carlo sampling + bitmask reachability + softmax ----------------
// grid 64 (img), 256 threads (1 thread = 1 sample)
__global__ __launch_bounds__(256) void k_mc(const float* __restrict__ enoise,
    const float* __restrict__ us, const float* __restrict__ ud,
    const int* __restrict__ edges,
    const float* __restrict__ pcw, const float* __restrict__ lpcw,
    const float* __restrict__ l1mw, const float* __restrict__ lcatw,
    float* __restrict__ out) {
  int b = blockIdx.x, t = threadIdx.x;
  __shared__ __align__(16) float pc_s[120];
  __shared__ __align__(16) float lpc_s[120];
  __shared__ __align__(16) float l1m_s[120];
  __shared__ __align__(16) float lcat_s[36];
  __shared__ __align__(16) int einfo[120];
  __shared__ float red_s[256];
  if (t < 120) {
    pc_s[t] = pcw[b * 120 + t];
    lpc_s[t] = lpcw[b * 120 + t];
    l1m_s[t] = l1mw[b * 120 + t];
    int u = edges[2 * t], v = edges[2 * t + 1];
    int d = v - u;
    int isV = (d == 6 || d == -6) ? 1 : 0;
    int pos = d > 0 ? u : v;
    einfo[t] = pos | (isV << 6);
  }
  if (t < 36) lcat_s[t] = lcatw[b * 36 + t];
  __syncthreads();

  float logw = 0.f;
  u64 H = 0, V = 0;
  {
    const float4* np = (const float4*)(enoise + ((size_t)(b * 256 + t)) * 120);
#pragma unroll
    for (int q = 0; q < 30; ++q) {
      float4 nz = np[q];
      float4 p4 = ((const float4*)pc_s)[q];
      float4 lp4 = ((const float4*)lpc_s)[q];
      float4 lm4 = ((const float4*)l1m_s)[q];
      int4 e4 = ((const int4*)einfo)[q];
      float nv[4] = {nz.x, nz.y, nz.z, nz.w};
      float pv[4] = {p4.x, p4.y, p4.z, p4.w};
      float lv[4] = {lp4.x, lp4.y, lp4.z, lp4.w};
      float mv[4] = {lm4.x, lm4.y, lm4.z, lm4.w};
      int ev[4] = {e4.x, e4.y, e4.z, e4.w};
#pragma unroll
      for (int r = 0; r < 4; ++r) {
        bool conn = nv[r] < pv[r];
        logw += conn ? lv[r] : mv[r];
        if (conn) {
          u64 bit = 1ull << (ev[r] & 63);
          if (ev[r] & 64) V |= bit; else H |= bit;
        }
      }
    }
  }
  int si = 0, di = 0;
  {
    const float4* up = (const float4*)(us + ((size_t)(b * 256 + t)) * 36);
    float best = -1e30f;
#pragma unroll
    for (int q = 0; q < 9; ++q) {
      float4 uv = up[q];
      float4 lc4 = ((const float4*)lcat_s)[q];
      float vv[4] = {uv.x, uv.y, uv.z, uv.w};
      float lc[4] = {lc4.x, lc4.y, lc4.z, lc4.w};
#pragma unroll
      for (int r = 0; r < 4; ++r) {
        float u = fminf(fmaxf(vv[r], EPSF), 1.f - EPSF);
        float gq = -logf(-logf(u));
        float val = lc[r] + gq;
        if (val > best) { best = val; si = q * 4 + r; }
      }
    }
  }
  {
    const float4* up = (const float4*)(ud + ((size_t)(b * 256 + t)) * 36);
    float best = -1e30f;
#pragma unroll
    for (int q = 0; q < 9; ++q) {
      float4 uv = up[q];
      float4 lc4 = ((const float4*)lcat_s)[q];
      float vv[4] = {uv.x, uv.y, uv.z, uv.w};
      float lc[4] = {lc4.x, lc4.y, lc4.z, lc4.w};
#pragma unroll
      for (int r = 0; r < 4; ++r) {
        float u = fminf(fmaxf(vv[r], EPSF), 1.f - EPSF);
        float gq = -logf(-logf(u));
        float val = lc[r] + gq;
        if (val > best) { best = val; di = q * 4 + r; }
      }
    }
  }
  logw += lcat_s[si] + lcat_s[di];

  u64 comp = 1ull << si;
  while (true) {
    u64 prev = comp;
    comp |= ((comp & H) << 1) | ((comp >> 1) & H);
    comp |= ((comp & V) << 6) | ((comp >> 6) & V);
    if (comp == prev) break;
  }
  float ex;
  if (si == di) ex = (comp != (1ull << si)) ? 1.f : 0.f;
  else ex = ((comp >> di) & 1ull) ? 1.f : 0.f;

  red_s[t] = logw; __syncthreads();
  for (int off = 128; off > 0; off >>= 1) {
    if (t < off) red_s[t] = fmaxf(red_s[t], red_s[t + off]);
    __syncthreads();
  }
  float m = red_s[0]; __syncthreads();
  float evx = expf(logw - m);
  red_s[t] = evx; __syncthreads();
  for (int off = 128; off > 0; off >>= 1) {
    if (t < off) red_s[t] += red_s[t + off];
    __syncthreads();
  }
  float den = red_s[0]; __syncthreads();
  red_s[t] = evx * ex; __syncthreads();
  for (int off = 128; off > 0; off >>= 1) {
    if (t < off) red_s[t] += red_s[t + off];
    __syncthreads();
  }
  if (t == 0) {
    float p1v = red_s[0] / den;
    out[b * 2] = 1.f - p1v;
    out[b * 2 + 1] = p1v;
  }
}

extern "C" void kernel_launch(void* const* d_in, const int* in_sizes, int n_in,
                              void* d_out, int out_size, void* d_ws, size_t ws_size,
                              hipStream_t stream) {
  const float* image = (const float*)d_in[0];
  const float* enoise = (const float*)d_in[1];
  const float* us = (const float*)d_in[2];
  const float* udn = (const float*)d_in[3];
  const float* cw1 = (const float*)d_in[4];
  const float* cb1 = (const float*)d_in[5];
  const float* cw2 = (const float*)d_in[6];
  const float* cb2 = (const float*)d_in[7];
  const float* cw3 = (const float*)d_in[8];
  const float* cb3 = (const float*)d_in[9];
  const float* cw4 = (const float*)d_in[10];
  const float* cb4 = (const float*)d_in[11];
  const float* wc1 = (const float*)d_in[12];
  const float* bc1 = (const float*)d_in[13];
  const float* wc2 = (const float*)d_in[14];
  const float* bc2 = (const float*)d_in[15];
  const float* we1 = (const float*)d_in[16];
  const float* be1 = (const float*)d_in[17];
  const float* we2 = (const float*)d_in[18];
  const float* be2 = (const float*)d_in[19];
  const int* edges = (const int*)d_in[20];

  float* ws = (float*)d_ws;
  float* c1 = ws;                  // 64*32*784
  float* p1w = ws + 1605632;       // 64*32*144
  float* c3 = ws + 1900544;        // 64*64*64
  float* emb = ws + 2162688;       // 64*256
  float* pcw = ws + 2179072;
  float* lpcw = ws + 2186752;
  float* l1mw = ws + 2194432;
  float* lcatw = ws + 2202112;
  float* outp = (float*)d_out;

  k_conv1<<<dim3(4, 64), dim3(512), 0, stream>>>(image, cw1, cb1, c1);
  k_conv2<<<dim3(4, 64), dim3(1024), 0, stream>>>(c1, cw2, cb2, p1w);
  k_conv3<<<dim3(8, 64), dim3(256), 0, stream>>>(p1w, cw3, cb3, c3);
  k_conv4<<<dim3(8, 64), dim3(256), 0, stream>>>(c3, cw4, cb4, emb);
  k_heads<<<dim3(2, 64), dim3(256), 0, stream>>>(emb, wc1, bc1, wc2, bc2,
                                                 we1, be1, we2, be2,
                                                 pcw, lpcw, l1mw, lcatw);
  k_mc<<<dim3(64), dim3(256), 0, stream>>>(enoise, us, udn, edges,
                                           pcw, lpcw, l1mw, lcatw, outp);
}

// Round 6
// 118.742 us; speedup vs baseline: 1.1389x; 1.0689x over previous
//
#include <hip/hip_runtime.h>

typedef unsigned long long u64;
#define EPSF 1e-6f

// ---------------- K1: conv1 1->32ch, 32x32 -> 28x28 ----------------
// grid (4 slabs of 8 oc, 64 img), 512 threads = (rowhalf:2) x (oc:8) x (x:32).
__global__ __launch_bounds__(512) void k_conv1(const float* __restrict__ img,
                                               const float* __restrict__ cw1,
                                               const float* __restrict__ cb1,
                                               float* __restrict__ c1) {
  int slab = blockIdx.x, b = blockIdx.y;
  __shared__ float simg[32 * 33];
  for (int k = threadIdx.x; k < 1024; k += 512) {
    int y = k >> 5, x = k & 31;
    simg[y * 33 + x] = img[b * 1024 + k];
  }
  int half = threadIdx.x >> 8;      // 0: out rows 0..13, 1: rows 14..27
  int u = threadIdx.x & 255;
  int ocl = u >> 5;
  int x = u & 31;
  int oc = slab * 8 + ocl;
  int y0 = half * 14;
  float w[25];
#pragma unroll
  for (int k = 0; k < 25; ++k) w[k] = cw1[oc * 25 + k];
  float bias = cb1[oc];
  __syncthreads();
  if (x < 28) {
    float acc[5];
#pragma unroll
    for (int k = 0; k < 5; ++k) acc[k] = bias;
    float* outp = c1 + (b * 32 + oc) * 784 + x;
#pragma unroll
    for (int rr = 0; rr < 18; ++rr) {
      int r = y0 + rr;
      float in[5];
#pragma unroll
      for (int c = 0; c < 5; ++c) in[c] = simg[r * 33 + x + c];
#pragma unroll
      for (int ky = 0; ky < 5; ++ky) {
        if (rr < ky || rr - ky > 13) continue;  // compile-time pruned
        int slot = (rr - ky) % 5;
#pragma unroll
        for (int kx = 0; kx < 5; ++kx)
          acc[slot] = fmaf(w[ky * 5 + kx], in[kx], acc[slot]);
      }
      if (rr >= 4) {
        int slot = (rr - 4) % 5;
        outp[(y0 + rr - 4) * 28] = acc[slot];
        acc[slot] = bias;
      }
    }
  }
}

// ---------------- K2: conv2 32->32ch, 28x28 -> 24x24, fused 2x2 maxpool -> 12x12 --------
// grid (4 ocq of 8 oc, 64 img) = 256 blocks, 1024 threads = 16 waves (4/SIMD).
// Full image in LDS with ROW STRIDE 29 (bank-conflict: max 3-chain instead of 4-way).
// Wave = (ocpair: 4) x (ic-quarter: 4): each wave computes 2 oc over 8 ic, so each
// 49-float window read feeds 450 FMAs (2x read economy vs 1 oc/wave).
// Weights = wave-uniform s_loads. Lane = 3x3 patch (64 lanes x 9 = 576 = 24x24).
__global__ __launch_bounds__(1024) void k_conv2(const float* __restrict__ c1,
                                                const float* __restrict__ cw2,
                                                const float* __restrict__ cb2,
                                                float* __restrict__ p1w) {
  int ocq = blockIdx.x, b = blockIdx.y;
  __shared__ float smem[25984];   // 103.9 KB: sInp[32][28][29]; aliased after compute:
                                  //   slot0 @0 (4608), slot1 @4608, cbuf @9216 (4608)
  int t = threadIdx.x;
  {  // stage: coalesced float4 global reads, scalar LDS writes into stride-29 rows
    const float4* src = (const float4*)(c1 + (size_t)b * 25088);
    for (int k = t; k < 6272; k += 1024) {
      float4 v = src[k];
      int ic = k / 196, rem = k % 196;
      int row = rem / 7, c4 = rem % 7;
      float* d = smem + ic * 812 + row * 29 + c4 * 4;
      d[0] = v.x; d[1] = v.y; d[2] = v.z; d[3] = v.w;
    }
  }
  int w = __builtin_amdgcn_readfirstlane(t >> 6);   // wave id
  int opair = w & 3;                                // oc pair within the 8-oc slab
  int icq = w >> 2;                                 // ic quarter: 8 ic each
  int l = t & 63;
  int py = l >> 3, px = l & 7;                      // 3x3 patch origin (3py, 3px)
  int oc0 = ocq * 8 + opair * 2;
  const float* wApt = cw2 + (size_t)oc0 * 800 + icq * 200;   // SGPR base, oc0
  const float* wBpt = wApt + 800;                            // oc0+1
  float acc[2][9];
#pragma unroll
  for (int j = 0; j < 2; ++j)
#pragma unroll
    for (int e = 0; e < 9; ++e) acc[j][e] = 0.f;
  __syncthreads();

  const float* base0 = smem + icq * 8 * 812 + (3 * py) * 29 + 3 * px;
#pragma unroll
  for (int ic = 0; ic < 8; ++ic) {
    float wa[25], wb[25];
#pragma unroll
    for (int k = 0; k < 25; ++k) { wa[k] = wApt[ic * 25 + k]; wb[k] = wBpt[ic * 25 + k]; }
    const float* base = base0 + ic * 812;
#pragma unroll
    for (int rr = 0; rr < 7; ++rr) {
      float win[7];
#pragma unroll
      for (int m = 0; m < 7; ++m) win[m] = base[rr * 29 + m];
#pragma unroll
      for (int i = 0; i < 3; ++i) {
        if (i > rr || rr - i > 4) continue;  // compile-time pruned
        int ky = rr - i;
#pragma unroll
        for (int kx = 0; kx < 5; ++kx) {
#pragma unroll
          for (int jj = 0; jj < 3; ++jj) {
            acc[0][i * 3 + jj] = fmaf(wa[ky * 5 + kx], win[jj + kx], acc[0][i * 3 + jj]);
            acc[1][i * 3 + jj] = fmaf(wb[ky * 5 + kx], win[jj + kx], acc[1][i * 3 + jj]);
          }
        }
      }
    }
  }

  __syncthreads();   // compute done -> image buffer dead, safe to alias
  float* slot0 = smem;
  float* slot1 = smem + 4608;
  float* cbuf = smem + 9216;    // [8 oc][24][24] conv(+bias) for pooling
  // chunk addr for (opair, j, lane): stride 9 -> lanes hit all banks 2-way (free)
  if (icq >= 2) {
    float* d = (icq == 2) ? slot0 : slot1;
#pragma unroll
    for (int j = 0; j < 2; ++j)
#pragma unroll
      for (int e = 0; e < 9; ++e) d[((opair * 2 + j) * 64 + l) * 9 + e] = acc[j][e];
  }
  __syncthreads();
  if (icq == 0) {
#pragma unroll
    for (int j = 0; j < 2; ++j)
#pragma unroll
      for (int e = 0; e < 9; ++e) acc[j][e] += slot0[((opair * 2 + j) * 64 + l) * 9 + e];
  }
  if (icq == 1) {
#pragma unroll
    for (int j = 0; j < 2; ++j)
#pragma unroll
      for (int e = 0; e < 9; ++e) acc[j][e] += slot1[((opair * 2 + j) * 64 + l) * 9 + e];
  }
  __syncthreads();
  if (icq == 1) {
#pragma unroll
    for (int j = 0; j < 2; ++j)
#pragma unroll
      for (int e = 0; e < 9; ++e) slot0[((opair * 2 + j) * 64 + l) * 9 + e] = acc[j][e];
  }
  __syncthreads();
  if (icq == 0) {
#pragma unroll
    for (int j = 0; j < 2; ++j) {
      float bias = cb2[oc0 + j];
#pragma unroll
      for (int i = 0; i < 3; ++i)
#pragma unroll
        for (int jj = 0; jj < 3; ++jj)
          cbuf[(opair * 2 + j) * 576 + (3 * py + i) * 24 + 3 * px + jj] =
              acc[j][i * 3 + jj] + slot0[((opair * 2 + j) * 64 + l) * 9 + i * 3 + jj] + bias;
    }
  }
  __syncthreads();
  // fused 2x2 maxpool -> p1w[img][32][12][12]
  for (int k = t; k < 1152; k += 1024) {
    int o = k / 144, rem = k % 144;
    int PY = rem / 12, PX = rem % 12;
    const float* b0 = cbuf + o * 576 + (2 * PY) * 24 + 2 * PX;
    float m = fmaxf(fmaxf(b0[0], b0[1]), fmaxf(b0[24], b0[25]));
    p1w[((size_t)b * 32 + ocq * 8 + o) * 144 + PY * 12 + PX] = m;
  }
}

// ---------------- K3: conv3 32->64ch, 12x12 -> 8x8 ----------------
// grid (8 groups of 8 oc, 64 img) = 512 blocks, 256 threads = g:16(2ic) x (ocg:2 x row:8).
__global__ __launch_bounds__(256) void k_conv3(const float* __restrict__ p1w,
                                               const float* __restrict__ cw3,
                                               const float* __restrict__ cb3,
                                               float* __restrict__ c3) {
  int oc8 = blockIdx.x, b = blockIdx.y;
  __shared__ float smem[11008];  // w3s 6400 | ins 4608 ; reduce aliases [0..4096)
  float* w3s = smem;
  float* ins = smem + 6400;
  int t = threadIdx.x;
  {
    const float4* src = (const float4*)(p1w + b * 32 * 144);
    float4* dst = (float4*)ins;
    for (int k = t; k < 1152; k += 256) dst[k] = src[k];
  }
  {
    const float4* src = (const float4*)(cw3 + oc8 * 8 * 800);
    for (int k4 = t; k4 < 1600; k4 += 256) {
      float4 v = src[k4];
      float vv[4] = {v.x, v.y, v.z, v.w};
      int k = k4 * 4;
#pragma unroll
      for (int r = 0; r < 4; ++r) {
        int kk = k + r;
        int o = kk / 800, rest = kk % 800;
        w3s[rest * 8 + o] = vv[r];
      }
    }
  }
  int g = t >> 4, p = t & 15;
  int ocg = p >> 3, row = p & 7;
  float acc[4][8];
#pragma unroll
  for (int j = 0; j < 4; ++j)
#pragma unroll
    for (int c = 0; c < 8; ++c) acc[j][c] = 0.f;
  __syncthreads();
#pragma unroll
  for (int icl = 0; icl < 2; ++icl) {
    int ic = g + icl * 16;
#pragma unroll
    for (int ky = 0; ky < 5; ++ky) {
      const float4* rp = (const float4*)(ins + ic * 144 + (row + ky) * 12);
      float win[12];
#pragma unroll
      for (int q = 0; q < 3; ++q) {
        float4 v = rp[q];
        win[4 * q] = v.x; win[4 * q + 1] = v.y; win[4 * q + 2] = v.z; win[4 * q + 3] = v.w;
      }
      const float* wb = w3s + (ic * 25 + ky * 5) * 8 + ocg * 4;
#pragma unroll
      for (int kx = 0; kx < 5; ++kx) {
        float wq[4];
        *(float4*)wq = *(const float4*)(wb + kx * 8);
#pragma unroll
        for (int c = 0; c < 8; ++c) {
#pragma unroll
          for (int j = 0; j < 4; ++j) acc[j][c] = fmaf(wq[j], win[c + kx], acc[j][c]);
        }
      }
    }
  }
  // 16-way reduce tree, chunk = 16 pos x 32 = 512 floats
  float* buf = smem;
  __syncthreads();
  if (g >= 8) {
    float* d = buf + (g - 8) * 512 + p * 32;
#pragma unroll
    for (int j = 0; j < 4; ++j)
#pragma unroll
      for (int c = 0; c < 8; ++c) d[j * 8 + c] = acc[j][c];
  }
  __syncthreads();
  if (g < 8) {
    const float* s = buf + g * 512 + p * 32;
#pragma unroll
    for (int j = 0; j < 4; ++j)
#pragma unroll
      for (int c = 0; c < 8; ++c) acc[j][c] += s[j * 8 + c];
  }
  __syncthreads();
  if (g >= 4 && g < 8) {
    float* d = buf + (g - 4) * 512 + p * 32;
#pragma unroll
    for (int j = 0; j < 4; ++j)
#pragma unroll
      for (int c = 0; c < 8; ++c) d[j * 8 + c] = acc[j][c];
  }
  __syncthreads();
  if (g < 4) {
    const float* s = buf + g * 512 + p * 32;
#pragma unroll
    for (int j = 0; j < 4; ++j)
#pragma unroll
      for (int c = 0; c < 8; ++c) acc[j][c] += s[j * 8 + c];
  }
  __syncthreads();
  if (g == 2 || g == 3) {
    float* d = buf + (g - 2) * 512 + p * 32;
#pragma unroll
    for (int j = 0; j < 4; ++j)
#pragma unroll
      for (int c = 0; c < 8; ++c) d[j * 8 + c] = acc[j][c];
  }
  __syncthreads();
  if (g < 2) {
    const float* s = buf + g * 512 + p * 32;
#pragma unroll
    for (int j = 0; j < 4; ++j)
#pragma unroll
      for (int c = 0; c < 8; ++c) acc[j][c] += s[j * 8 + c];
  }
  __syncthreads();
  if (g == 1) {
    float* d = buf + p * 32;
#pragma unroll
    for (int j = 0; j < 4; ++j)
#pragma unroll
      for (int c = 0; c < 8; ++c) d[j * 8 + c] = acc[j][c];
  }
  __syncthreads();
  if (g == 0) {
    const float* s = buf + p * 32;
#pragma unroll
    for (int j = 0; j < 4; ++j) {
      float bias = cb3[oc8 * 8 + ocg * 4 + j];
      float4 v0, v1;
      v0.x = acc[j][0] + s[j * 8 + 0] + bias; v0.y = acc[j][1] + s[j * 8 + 1] + bias;
      v0.z = acc[j][2] + s[j * 8 + 2] + bias; v0.w = acc[j][3] + s[j * 8 + 3] + bias;
      v1.x = acc[j][4] + s[j * 8 + 4] + bias; v1.y = acc[j][5] + s[j * 8 + 5] + bias;
      v1.z = acc[j][6] + s[j * 8 + 6] + bias; v1.w = acc[j][7] + s[j * 8 + 7] + bias;
      float* op = c3 + (b * 64 + oc8 * 8 + ocg * 4 + j) * 64 + row * 8;
      *(float4*)op = v0; *(float4*)(op + 4) = v1;
    }
  }
}

// ---------------- K4: conv4 64->64ch, 8x8 -> 4x4, fused pool -> emb[256] ----------------
// grid (8 groups of 8 oc, 64 img) = 512 blocks, 256 threads = g:32(2ic) x (ocg:2 x row:4).
__global__ __launch_bounds__(256) void k_conv4(const float* __restrict__ c3,
                                               const float* __restrict__ cw4,
                                               const float* __restrict__ cb4,
                                               float* __restrict__ emb) {
  int oc8 = blockIdx.x, b = blockIdx.y;
  __shared__ float smem[17152];  // w4s 12800 | ins 64*68 ; reduce aliases [0..2048), pb @2048
  float* w4s = smem;
  float* ins = smem + 12800;     // padded stride 68 per ic
  int t = threadIdx.x;
  {
    const float4* src = (const float4*)(c3 + b * 4096);
    for (int k = t; k < 1024; k += 256) {
      int ic = k >> 4, q = k & 15;
      *(float4*)(ins + ic * 68 + q * 4) = src[k];
    }
  }
  {
    const float4* src = (const float4*)(cw4 + oc8 * 8 * 1600);
    for (int k4 = t; k4 < 3200; k4 += 256) {
      float4 v = src[k4];
      float vv[4] = {v.x, v.y, v.z, v.w};
      int k = k4 * 4;
#pragma unroll
      for (int r = 0; r < 4; ++r) {
        int kk = k + r;
        int o = kk / 1600, rest = kk % 1600;
        w4s[rest * 8 + o] = vv[r];
      }
    }
  }
  int g = t >> 3, p = t & 7;
  int ocg = p >> 2, row = p & 3;
  float acc[4][4];
#pragma unroll
  for (int j = 0; j < 4; ++j)
#pragma unroll
    for (int c = 0; c < 4; ++c) acc[j][c] = 0.f;
  __syncthreads();
#pragma unroll
  for (int icl = 0; icl < 2; ++icl) {
    int ic = g + icl * 32;
#pragma unroll
    for (int ky = 0; ky < 5; ++ky) {
      const float4* rp = (const float4*)(ins + ic * 68 + (row + ky) * 8);
      float win[8];
#pragma unroll
      for (int q = 0; q < 2; ++q) {
        float4 v = rp[q];
        win[4 * q] = v.x; win[4 * q + 1] = v.y; win[4 * q + 2] = v.z; win[4 * q + 3] = v.w;
      }
      const float* wb = w4s + (ic * 25 + ky * 5) * 8 + ocg * 4;
#pragma unroll
      for (int kx = 0; kx < 5; ++kx) {
        float wq[4];
        *(float4*)wq = *(const float4*)(wb + kx * 8);
#pragma unroll
        for (int c = 0; c < 4; ++c) {
#pragma unroll
          for (int j = 0; j < 4; ++j) acc[j][c] = fmaf(wq[j], win[c + kx], acc[j][c]);
        }
      }
    }
  }
  // 32-way reduce tree, chunk = 8 pos x 16 = 128 floats
  float* buf = smem;
#pragma unroll
  for (int half = 16; half >= 1; half >>= 1) {
    __syncthreads();
    if (g >= half && g < 2 * half) {
      float* d = buf + (g - half) * 128 + p * 16;
#pragma unroll
      for (int j = 0; j < 4; ++j)
#pragma unroll
        for (int c = 0; c < 4; ++c) d[j * 4 + c] = acc[j][c];
    }
    __syncthreads();
    if (g < half) {
      const float* s = buf + g * 128 + p * 16;
#pragma unroll
      for (int j = 0; j < 4; ++j)
#pragma unroll
        for (int c = 0; c < 4; ++c) acc[j][c] += s[j * 4 + c];
    }
  }
  float* pb = buf + 2048;  // [8 oc][4 rows][4 cols]
  if (g == 0) {
#pragma unroll
    for (int j = 0; j < 4; ++j) {
      float bias = cb4[oc8 * 8 + ocg * 4 + j];
#pragma unroll
      for (int c = 0; c < 4; ++c) pb[(ocg * 4 + j) * 16 + row * 4 + c] = acc[j][c] + bias;
    }
  }
  __syncthreads();
  if (t < 32) {  // 2x2 pool -> emb
    int o = t >> 2, q = t & 3, py = q >> 1, px = q & 1;
    const float* b0 = pb + o * 16 + (2 * py) * 4 + 2 * px;
    float m = fmaxf(fmaxf(b0[0], b0[1]), fmaxf(b0[4], b0[5]));
    emb[b * 256 + (oc8 * 8 + o) * 4 + py * 2 + px] = m;
  }
}

// ---------------- K5a: MLP heads -> pc, log(pc), log1p(-pc), logcat ----------------
// grid (2 heads, 64 img), 256 threads
__global__ __launch_bounds__(256) void k_heads(const float* __restrict__ emb,
    const float* __restrict__ wc1, const float* __restrict__ bc1,
    const float* __restrict__ wc2, const float* __restrict__ bc2,
    const float* __restrict__ we1, const float* __restrict__ be1,
    const float* __restrict__ we2, const float* __restrict__ be2,
    float* __restrict__ pcw, float* __restrict__ lpcw,
    float* __restrict__ l1mw, float* __restrict__ lcatw) {
  int head = blockIdx.x, b = blockIdx.y;
  int t = threadIdx.x;
  __shared__ float e_s[256], h_s[256];
  __shared__ float aux;
  e_s[t] = emb[b * 256 + t];
  __syncthreads();
  const float* W1 = head ? we1 : wc1;
  const float* B1 = head ? be1 : bc1;
  float s = B1[t];
  for (int i = 0; i < 256; i += 4) {
    s = fmaf(e_s[i], W1[i * 256 + t], s);
    s = fmaf(e_s[i + 1], W1[(i + 1) * 256 + t], s);
    s = fmaf(e_s[i + 2], W1[(i + 2) * 256 + t], s);
    s = fmaf(e_s[i + 3], W1[(i + 3) * 256 + t], s);
  }
  h_s[t] = fmaxf(s, 0.f);
  __syncthreads();
  int NO = head ? 36 : 120;
  const float* W2 = head ? we2 : wc2;
  const float* B2 = head ? be2 : bc2;
  if (t < NO) {
    float s2 = B2[t];
    for (int i = 0; i < 256; ++i) s2 = fmaf(h_s[i], W2[i * NO + t], s2);
    float p = 1.f / (1.f + expf(-s2));
    p = fminf(fmaxf(p, EPSF), 1.f - EPSF);
    if (head == 0) {
      pcw[b * 120 + t] = p;
      lpcw[b * 120 + t] = logf(p);
      l1mw[b * 120 + t] = log1pf(-p);
    } else {
      e_s[t] = p;  // reuse as pe storage
    }
  }
  if (head == 1) {
    __syncthreads();
    if (t == 0) {
      float sm = 0.f;
      for (int j2 = 0; j2 < 36; ++j2) sm += e_s[j2];
      aux = sm;
    }
    __syncthreads();
    if (t < 36) lcatw[b * 36 + t] = logf(e_s[t] / aux);
  }
}

// ---------------- K5b: Monte-Carlo sampling + bitmask reachability + softmax ----------------
// grid 64 (img), 256 threads (1 thread = 1 sample)
__global__ __launch_bounds__(256) void k_mc(const float* __restrict__ enoise,
    const float* __restrict__ us, const float* __restrict__ ud,
    const int* __restrict__ edges,
    const float* __restrict__ pcw, const float* __restrict__ lpcw,
    const float* __restrict__ l1mw, const float* __restrict__ lcatw,
    float* __restrict__ out) {
  int b = blockIdx.x, t = threadIdx.x;
  __shared__ __align__(16) float pc_s[120];
  __shared__ __align__(16) float lpc_s[120];
  __shared__ __align__(16) float l1m_s[120];
  __shared__ __align__(16) float lcat_s[36];
  __shared__ __align__(16) int einfo[120];
  __shared__ float red_s[256];
  if (t < 120) {
    pc_s[t] = pcw[b * 120 + t];
    lpc_s[t] = lpcw[b * 120 + t];
    l1m_s[t] = l1mw[b * 120 + t];
    int u = edges[2 * t], v = edges[2 * t + 1];
    int d = v - u;
    int isV = (d == 6 || d == -6) ? 1 : 0;
    int pos = d > 0 ? u : v;
    einfo[t] = pos | (isV << 6);
  }
  if (t < 36) lcat_s[t] = lcatw[b * 36 + t];
  __syncthreads();

  float logw = 0.f;
  u64 H = 0, V = 0;
  {
    const float4* np = (const float4*)(enoise + ((size_t)(b * 256 + t)) * 120);
#pragma unroll
    for (int q = 0; q < 30; ++q) {
      float4 nz = np[q];
      float4 p4 = ((const float4*)pc_s)[q];
      float4 lp4 = ((const float4*)lpc_s)[q];
      float4 lm4 = ((const float4*)l1m_s)[q];
      int4 e4 = ((const int4*)einfo)[q];
      float nv[4] = {nz.x, nz.y, nz.z, nz.w};
      float pv[4] = {p4.x, p4.y, p4.z, p4.w};
      float lv[4] = {lp4.x, lp4.y, lp4.z, lp4.w};
      float mv[4] = {lm4.x, lm4.y, lm4.z, lm4.w};
      int ev[4] = {e4.x, e4.y, e4.z, e4.w};
#pragma unroll
      for (int r = 0; r < 4; ++r) {
        bool conn = nv[r] < pv[r];
        logw += conn ? lv[r] : mv[r];
        if (conn) {
          u64 bit = 1ull << (ev[r] & 63);
          if (ev[r] & 64) V |= bit; else H |= bit;
        }
      }
    }
  }
  int si = 0, di = 0;
  {
    const float4* up = (const float4*)(us + ((size_t)(b * 256 + t)) * 36);
    float best = -1e30f;
#pragma unroll
    for (int q = 0; q < 9; ++q) {
      float4 uv = up[q];
      float4 lc4 = ((const float4*)lcat_s)[q];
      float vv[4] = {uv.x, uv.y, uv.z, uv.w};
      float lc[4] = {lc4.x, lc4.y, lc4.z, lc4.w};
#pragma unroll
      for (int r = 0; r < 4; ++r) {
        float u = fminf(fmaxf(vv[r], EPSF), 1.f - EPSF);
        float gq = -logf(-logf(u));
        float val = lc[r] + gq;
        if (val > best) { best = val; si = q * 4 + r; }
      }
    }
  }
  {
    const float4* up = (const float4*)(ud + ((size_t)(b * 256 + t)) * 36);
    float best = -1e30f;
#pragma unroll
    for (int q = 0; q < 9; ++q) {
      float4 uv = up[q];
      float4 lc4 = ((const float4*)lcat_s)[q];
      float vv[4] = {uv.x, uv.y, uv.z, uv.w};
      float lc[4] = {lc4.x, lc4.y, lc4.z, lc4.w};
#pragma unroll
      for (int r = 0; r < 4; ++r) {
        float u = fminf(fmaxf(vv[r], EPSF), 1.f - EPSF);
        float gq = -logf(-logf(u));
        float val = lc[r] + gq;
        if (val > best) { best = val; di = q * 4 + r; }
      }
    }
  }
  logw += lcat_s[si] + lcat_s[di];

  u64 comp = 1ull << si;
  while (true) {
    u64 prev = comp;
    comp |= ((comp & H) << 1) | ((comp >> 1) & H);
    comp |= ((comp & V) << 6) | ((comp >> 6) & V);
    if (comp == prev) break;
  }
  float ex;
  if (si == di) ex = (comp != (1ull << si)) ? 1.f : 0.f;
  else ex = ((comp >> di) & 1ull) ? 1.f : 0.f;

  red_s[t] = logw; __syncthreads();
  for (int off = 128; off > 0; off >>= 1) {
    if (t < off) red_s[t] = fmaxf(red_s[t], red_s[t + off]);
    __syncthreads();
  }
  float m = red_s[0]; __syncthreads();
  float evx = expf(logw - m);
  red_s[t] = evx; __syncthreads();
  for (int off = 128; off > 0; off >>= 1) {
    if (t < off) red_s[t] += red_s[t + off];
    __syncthreads();
  }
  float den = red_s[0]; __syncthreads();
  red_s[t] = evx * ex; __syncthreads();
  for (int off = 128; off > 0; off >>= 1) {
    if (t < off) red_s[t] += red_s[t + off];
    __syncthreads();
  }
  if (t == 0) {
    float p1v = red_s[0] / den;
    out[b * 2] = 1.f - p1v;
    out[b * 2 + 1] = p1v;
  }
}

extern "C" void kernel_launch(void* const* d_in, const int* in_sizes, int n_in,
                              void* d_out, int out_size, void* d_ws, size_t ws_size,
                              hipStream_t stream) {
  const float* image = (const float*)d_in[0];
  const float* enoise = (const float*)d_in[1];
  const float* us = (const float*)d_in[2];
  const float* udn = (const float*)d_in[3];
  const float* cw1 = (const float*)d_in[4];
  const float* cb1 = (const float*)d_in[5];
  const float* cw2 = (const float*)d_in[6];
  const float* cb2 = (const float*)d_in[7];
  const float* cw3 = (const float*)d_in[8];
  const float* cb3 = (const float*)d_in[9];
  const float* cw4 = (const float*)d_in[10];
  const float* cb4 = (const float*)d_in[11];
  const float* wc1 = (const float*)d_in[12];
  const float* bc1 = (const float*)d_in[13];
  const float* wc2 = (const float*)d_in[14];
  const float* bc2 = (const float*)d_in[15];
  const float* we1 = (const float*)d_in[16];
  const float* be1 = (const float*)d_in[17];
  const float* we2 = (const float*)d_in[18];
  const float* be2 = (const float*)d_in[19];
  const int* edges = (const int*)d_in[20];

  float* ws = (float*)d_ws;
  float* c1 = ws;                  // 64*32*784
  float* p1w = ws + 1605632;       // 64*32*144
  float* c3 = ws + 1900544;        // 64*64*64
  float* emb = ws + 2162688;       // 64*256
  float* pcw = ws + 2179072;
  float* lpcw = ws + 2186752;
  float* l1mw = ws + 2194432;
  float* lcatw = ws + 2202112;
  float* outp = (float*)d_out;

  k_conv1<<<dim3(4, 64), dim3(512), 0, stream>>>(image, cw1, cb1, c1);
  k_conv2<<<dim3(4, 64), dim3(1024), 0, stream>>>(c1, cw2, cb2, p1w);
  k_conv3<<<dim3(8, 64), dim3(256), 0, stream>>>(p1w, cw3, cb3, c3);
  k_conv4<<<dim3(8, 64), dim3(256), 0, stream>>>(c3, cw4, cb4, emb);
  k_heads<<<dim3(2, 64), dim3(256), 0, stream>>>(emb, wc1, bc1, wc2, bc2,
                                                 we1, be1, we2, be2,
                                                 pcw, lpcw, l1mw, lcatw);
  k_mc<<<dim3(64), dim3(256), 0, stream>>>(enoise, us, udn, edges,
                                           pcw, lpcw, l1mw, lcatw, outp);
}